// Round 1
// baseline (615.006 us; speedup 1.0000x reference)
//
#include <hip/hip_runtime.h>
#include <math.h>

#define GAMMA_ 0.1f
#define EPS_ 0.1f
constexpr int BLK = 256;

// ---------------- graph prep ----------------
__global__ void k_init(int* cnt, int n) {
  int i = blockIdx.x * BLK + threadIdx.x;
  if (i < n) cnt[i] = 0;
}

__global__ void k_count(const int* __restrict__ dst, int* cnt, int e) {
  int i = blockIdx.x * BLK + threadIdx.x;
  if (i < e) atomicAdd(&cnt[dst[i]], 1);
}

__global__ void k_scan1(const int* __restrict__ cnt, int* __restrict__ rowp,
                        int* __restrict__ bsum, int n) {
  __shared__ int s[BLK];
  int t = threadIdx.x;
  int i = blockIdx.x * BLK + t;
  int v = (i < n) ? cnt[i] : 0;
  s[t] = v; __syncthreads();
  for (int off = 1; off < BLK; off <<= 1) {
    int u = (t >= off) ? s[t - off] : 0;
    __syncthreads();
    s[t] += u;
    __syncthreads();
  }
  if (i < n) rowp[i] = s[t] - v;           // block-local exclusive
  if (t == BLK - 1) bsum[blockIdx.x] = s[t];
}

__global__ void k_scan2(const int* __restrict__ bsum, int* __restrict__ boff, int nb) {
  __shared__ int s[BLK];
  int t = threadIdx.x;
  int v = (t < nb) ? bsum[t] : 0;
  s[t] = v; __syncthreads();
  for (int off = 1; off < BLK; off <<= 1) {
    int u = (t >= off) ? s[t - off] : 0;
    __syncthreads();
    s[t] += u;
    __syncthreads();
  }
  if (t < nb) boff[t] = s[t] - v;          // exclusive
}

__global__ void k_scan3(const int* __restrict__ boff, int* __restrict__ rowp,
                        int* __restrict__ cnt, float* __restrict__ dinv, int n, int e) {
  int i = blockIdx.x * BLK + threadIdx.x;
  if (i < n) {
    rowp[i] += boff[blockIdx.x];
    dinv[i] = rsqrtf((float)cnt[i] + 1.0f);
    cnt[i] = 0;
    if (i == 0) rowp[n] = e;
  }
}

__global__ void k_fill(const int* __restrict__ src, const int* __restrict__ dst,
                       const int* __restrict__ rowp, int* __restrict__ cnt,
                       const float* __restrict__ dinv,
                       int* __restrict__ csrc, float* __restrict__ enorm, int e) {
  int i = blockIdx.x * BLK + threadIdx.x;
  if (i < e) {
    int d = dst[i], s = src[i];
    int pos = rowp[d] + atomicAdd(&cnt[d], 1);
    csrc[pos] = s;
    enorm[pos] = dinv[s] * dinv[d];
  }
}

// Mt[k][j] = (M^T)[k][j] = M[j][k] = W[j][k] - W[k][j] - gamma*delta
// lw1t[k][j] = lw1[j][k]
__global__ void k_prep(const float* __restrict__ W1, const float* __restrict__ W2,
                       const float* __restrict__ lw1,
                       float* __restrict__ Mt1, float* __restrict__ Mt2,
                       float* __restrict__ lw1t) {
  int idx = blockIdx.x * BLK + threadIdx.x;
  if (idx < 16384) {
    int k = idx >> 7, j = idx & 127;
    float g = (j == k) ? GAMMA_ : 0.f;
    Mt1[idx] = W1[j * 128 + k] - W1[k * 128 + j] - g;
    Mt2[idx] = W2[j * 128 + k] - W2[k * 128 + j] - g;
    lw1t[idx] = lw1[j * 128 + k];
  }
}

// ---------------- fp32 GEMM: C[nrows,BN] = A[nrows,128] @ B[128,BN] ----------------
// B given as B0 (cols 0..127) and optional B1 (cols 128..255), both row-major [128,128].
template<int BN, bool RELU_BIAS>
__global__ __launch_bounds__(256) void k_gemm(
    const float* __restrict__ A, int nrows,
    const float* __restrict__ B0, const float* __restrict__ B1,
    const float* __restrict__ bias, float* __restrict__ C) {
  constexpr int CG = BN / 4;      // col groups of 4
  constexpr int RG = 256 / CG;    // row groups of 4
  constexpr int BM = RG * 4;      // 16 (BN=256) or 32 (BN=128)
  __shared__ float As[BM * 128];
  const int t = threadIdx.x;
  const int row0 = blockIdx.x * BM;
  {
    const float4* Ag = (const float4*)(A + (size_t)row0 * 128);
    float4* Asv = (float4*)As;
    constexpr int NV = BM * 32;
    for (int i = t; i < NV; i += 256) {
      float4 v = {0.f, 0.f, 0.f, 0.f};
      if (row0 + (i >> 5) < nrows) v = Ag[i];
      Asv[i] = v;
    }
  }
  __syncthreads();
  const int tx = t % CG, ty = t / CG;
  const int cb = 4 * tx;
  const float* Bp = (BN == 256 && cb >= 128) ? (B1 + (cb - 128)) : (B0 + cb);
  const float* Ab = As + (ty * 4) * 128;
  float acc[4][4] = {};
#pragma unroll 4
  for (int k = 0; k < 128; ++k) {
    float4 b = *(const float4*)(Bp + (size_t)k * 128);
    float a0 = Ab[k], a1 = Ab[128 + k], a2 = Ab[256 + k], a3 = Ab[384 + k];
    acc[0][0] += a0 * b.x; acc[0][1] += a0 * b.y; acc[0][2] += a0 * b.z; acc[0][3] += a0 * b.w;
    acc[1][0] += a1 * b.x; acc[1][1] += a1 * b.y; acc[1][2] += a1 * b.z; acc[1][3] += a1 * b.w;
    acc[2][0] += a2 * b.x; acc[2][1] += a2 * b.y; acc[2][2] += a2 * b.z; acc[2][3] += a2 * b.w;
    acc[3][0] += a3 * b.x; acc[3][1] += a3 * b.y; acc[3][2] += a3 * b.z; acc[3][3] += a3 * b.w;
  }
#pragma unroll
  for (int i = 0; i < 4; ++i) {
    int r = row0 + ty * 4 + i;
    if (r >= nrows) continue;
    float4 v = {acc[i][0], acc[i][1], acc[i][2], acc[i][3]};
    if (RELU_BIAS) {
      v.x = fmaxf(v.x + bias[cb + 0], 0.f);
      v.y = fmaxf(v.y + bias[cb + 1], 0.f);
      v.z = fmaxf(v.z + bias[cb + 2], 0.f);
      v.w = fmaxf(v.w + bias[cb + 3], 0.f);
    }
    *(float4*)(C + (size_t)r * BN + cb) = v;
  }
}

// ---------------- fused aggregate + antisym combine (+relu) ----------------
// A = [N,256] rows: [ xw(128) | xm(128) ]
// out[i] = relu( xin[i] + 0.1*tanh( xm[i] + bias + xw[i]*dinv^2 + sum_e xw[src]*norm ) )
__global__ __launch_bounds__(256) void k_aggc(
    const float* __restrict__ A, const float* __restrict__ xin,
    const float* __restrict__ dinv,
    const int* __restrict__ rowp, const int* __restrict__ csrc,
    const float* __restrict__ enorm, const float* __restrict__ bias,
    float* __restrict__ out, int n) {
  int node = blockIdx.x * 2 + (threadIdx.x >> 7);
  int f = threadIdx.x & 127;
  if (node >= n) return;
  float di = dinv[node];
  float acc = A[(size_t)node * 256 + f] * di * di;
  int e0 = rowp[node], e1 = rowp[node + 1];
  for (int e = e0; e < e1; ++e) {
    int s = csrc[e];
    float w = enorm[e];
    acc += A[(size_t)s * 256 + f] * w;
  }
  float h = acc + A[(size_t)node * 256 + 128 + f] + bias[f];
  float o = xin[(size_t)node * 128 + f] + EPS_ * tanhf(h);
  out[(size_t)node * 128 + f] = fmaxf(o, 0.f);
}

// ---------------- fused final linear + log_softmax ----------------
__global__ __launch_bounds__(256) void k_logits(
    const float* __restrict__ X, const float* __restrict__ lw2,
    const float* __restrict__ lb2, float* __restrict__ out, int n) {
  __shared__ float wl[40 * 130];
  __shared__ float bl[40];
  for (int i = threadIdx.x; i < 40 * 128; i += 256) {
    int c = i >> 7, k = i & 127;
    wl[c * 130 + k] = lw2[i];
  }
  if (threadIdx.x < 40) bl[threadIdx.x] = lb2[threadIdx.x];
  __syncthreads();
  int wid = threadIdx.x >> 6, lane = threadIdx.x & 63;
  int row = blockIdx.x * 4 + wid;
  if (row >= n) return;
  const float* xr = X + (size_t)row * 128;
  float v = 0.f;
  if (lane < 40) {
    const float* wr = wl + lane * 130;
#pragma unroll 8
    for (int k = 0; k < 128; ++k) v += xr[k] * wr[k];
    v += bl[lane];
  }
  float m = (lane < 40) ? v : -INFINITY;
  for (int off = 32; off; off >>= 1) m = fmaxf(m, __shfl_xor(m, off));
  float ex = (lane < 40) ? expf(v - m) : 0.f;
  float ssum = ex;
  for (int off = 32; off; off >>= 1) ssum += __shfl_xor(ssum, off);
  float lse = m + logf(ssum);
  if (lane < 40) out[(size_t)row * 40 + lane] = v - lse;
}

// ---------------- launch ----------------
extern "C" void kernel_launch(void* const* d_in, const int* in_sizes, int n_in,
                              void* d_out, int out_size, void* d_ws, size_t ws_size,
                              hipStream_t stream) {
  const float* x   = (const float*)d_in[0];
  const int*   ei  = (const int*)d_in[1];
  const float* W1  = (const float*)d_in[2];
  const float* b1  = (const float*)d_in[3];
  const float* T1  = (const float*)d_in[4];
  const float* W2  = (const float*)d_in[5];
  const float* b2  = (const float*)d_in[6];
  const float* T2  = (const float*)d_in[7];
  const float* lw1 = (const float*)d_in[8];
  const float* lb1 = (const float*)d_in[9];
  const float* lw2 = (const float*)d_in[10];
  const float* lb2 = (const float*)d_in[11];
  const int N = in_sizes[0] / 128;
  const int E = in_sizes[1] / 2;
  const int* src = ei;
  const int* dst = ei + E;

  float* ws = (float*)d_ws;
  size_t o = 0;
  float* dinv = ws;             o += N;
  int* cnt = (int*)(ws + o);    o += N;
  int* rowp = (int*)(ws + o);   o += (size_t)(N + 4);
  int* csrc = (int*)(ws + o);   o += E;
  float* enorm = ws + o;        o += E;
  int* bsum = (int*)(ws + o);   o += 256;
  int* boff = (int*)(ws + o);   o += 256;
  float* Mt1 = ws + o;          o += 16384;
  float* Mt2 = ws + o;          o += 16384;
  float* lw1t = ws + o;         o += 16384;
  float* bufA = ws + o;         o += (size_t)N * 256;
  float* h1 = ws + o;           o += (size_t)N * 128;
  float* h2 = ws + o;           o += (size_t)N * 128;

  float* outp = (float*)d_out;
  float* x1 = outp + (size_t)N * 40;

  int nb_n = (N + BLK - 1) / BLK;   // 196
  int nb_e = (E + BLK - 1) / BLK;   // 3125

  k_init<<<nb_n, BLK, 0, stream>>>(cnt, N);
  k_count<<<nb_e, BLK, 0, stream>>>(dst, cnt, E);
  k_scan1<<<nb_n, BLK, 0, stream>>>(cnt, rowp, bsum, N);
  k_scan2<<<1, BLK, 0, stream>>>(bsum, boff, nb_n);
  k_scan3<<<nb_n, BLK, 0, stream>>>(boff, rowp, cnt, dinv, N, E);
  k_fill<<<nb_e, BLK, 0, stream>>>(src, dst, rowp, cnt, dinv, csrc, enorm, E);
  k_prep<<<64, BLK, 0, stream>>>(W1, W2, lw1, Mt1, Mt2, lw1t);

  // layer 1
  k_gemm<256, false><<<(N + 15) / 16, 256, 0, stream>>>(x, N, T1, Mt1, nullptr, bufA);
  k_aggc<<<(N + 1) / 2, 256, 0, stream>>>(bufA, x, dinv, rowp, csrc, enorm, b1, h1, N);
  // linear 1 + relu
  k_gemm<128, true><<<(N + 31) / 32, 256, 0, stream>>>(h1, N, lw1t, nullptr, lb1, h2);
  // layer 2
  k_gemm<256, false><<<(N + 15) / 16, 256, 0, stream>>>(h2, N, T2, Mt2, nullptr, bufA);
  k_aggc<<<(N + 1) / 2, 256, 0, stream>>>(bufA, h2, dinv, rowp, csrc, enorm, b2, x1, N);
  // linear 2 + log_softmax
  k_logits<<<(N + 3) / 4, 256, 0, stream>>>(x1, lw2, lb2, outp, N);
}

// Round 2
// 323.995 us; speedup vs baseline: 1.8982x; 1.8982x over previous
//
#include <hip/hip_runtime.h>
#include <hip/hip_bf16.h>
#include <math.h>

#define GAMMA_ 0.1f
#define EPS_ 0.1f
constexpr int BLK = 256;

typedef __attribute__((ext_vector_type(8))) short short8;
typedef __attribute__((ext_vector_type(4))) float f32x4;

__device__ inline float bflo(uint u) { union { uint i; float f; } v; v.i = u << 16; return v.f; }
__device__ inline float bfhi(uint u) { union { uint i; float f; } v; v.i = u & 0xffff0000u; return v.f; }
__device__ inline ushort f2bf(float f) {
  union { float f; uint i; } v; v.f = f;
  uint i = v.i;
  return (ushort)((i + 0x7fffu + ((i >> 16) & 1u)) >> 16);  // RNE
}

// ---------------- graph prep ----------------
__global__ void k_init(int* cnt, int n) {
  int i = blockIdx.x * BLK + threadIdx.x;
  if (i < n) cnt[i] = 0;
}

__global__ void k_count(const int* __restrict__ dst, int* cnt, int e) {
  int i = blockIdx.x * BLK + threadIdx.x;
  if (i < e) atomicAdd(&cnt[dst[i]], 1);
}

__global__ void k_scan1(const int* __restrict__ cnt, int* __restrict__ rowp,
                        int* __restrict__ bsum, int n) {
  __shared__ int s[BLK];
  int t = threadIdx.x;
  int i = blockIdx.x * BLK + t;
  int v = (i < n) ? cnt[i] : 0;
  s[t] = v; __syncthreads();
  for (int off = 1; off < BLK; off <<= 1) {
    int u = (t >= off) ? s[t - off] : 0;
    __syncthreads();
    s[t] += u;
    __syncthreads();
  }
  if (i < n) rowp[i] = s[t] - v;
  if (t == BLK - 1) bsum[blockIdx.x] = s[t];
}

__global__ void k_scan2(const int* __restrict__ bsum, int* __restrict__ boff, int nb) {
  __shared__ int s[BLK];
  int t = threadIdx.x;
  int v = (t < nb) ? bsum[t] : 0;
  s[t] = v; __syncthreads();
  for (int off = 1; off < BLK; off <<= 1) {
    int u = (t >= off) ? s[t - off] : 0;
    __syncthreads();
    s[t] += u;
    __syncthreads();
  }
  if (t < nb) boff[t] = s[t] - v;
}

__global__ void k_scan3(const int* __restrict__ boff, int* __restrict__ rowp,
                        int* __restrict__ cnt, float* __restrict__ dinv, int n, int e) {
  int i = blockIdx.x * BLK + threadIdx.x;
  if (i < n) {
    rowp[i] += boff[blockIdx.x];
    dinv[i] = rsqrtf((float)cnt[i] + 1.0f);
    cnt[i] = 0;
    if (i == 0) rowp[n] = e;
  }
}

__global__ void k_fill(const int* __restrict__ src, const int* __restrict__ dst,
                       const int* __restrict__ rowp, int* __restrict__ cnt,
                       const float* __restrict__ dinv,
                       int* __restrict__ csrc, float* __restrict__ enorm, int e) {
  int i = blockIdx.x * BLK + threadIdx.x;
  if (i < e) {
    int d = dst[i], s = src[i];
    int pos = rowp[d] + atomicAdd(&cnt[d], 1);
    csrc[pos] = s;
    enorm[pos] = dinv[s] * dinv[d];
  }
}

// ---------------- weight packing (bf16 MFMA fragment order) ----------------
// Bpk[((kt*4+q)*NC + c)*8 + j] = B[kt*32 + q*8 + j][c]
__global__ void k_pack(const float* __restrict__ W1, const float* __restrict__ T1,
                       const float* __restrict__ W2, const float* __restrict__ T2,
                       const float* __restrict__ lw1,
                       ushort* __restrict__ Bpk1, ushort* __restrict__ Bpk2,
                       ushort* __restrict__ Bpkl) {
  int idx = blockIdx.x * BLK + threadIdx.x;
  if (idx < 65536) {
    int which = idx >> 15;
    int e = idx & 32767;
    int k = e >> 8, c = e & 255;
    const float* W = which ? W2 : W1;
    const float* T = which ? T2 : T1;
    float v;
    if (c < 128) {
      v = T[k * 128 + c];
    } else {
      int cc = c - 128;  // (M^T)[k][cc] = M[cc][k] = W[cc][k] - W[k][cc] - g*delta
      v = W[cc * 128 + k] - W[k * 128 + cc] - ((cc == k) ? GAMMA_ : 0.f);
    }
    int kt = k >> 5, q = (k >> 3) & 3, j = k & 7;
    ushort* B = which ? Bpk2 : Bpk1;
    B[(((kt * 4 + q) * 256 + c) << 3) + j] = f2bf(v);
  } else {
    int e = idx - 65536;
    if (e < 16384) {
      int k = e >> 7, c = e & 127;
      float v = lw1[c * 128 + k];  // lw1^T[k][c]
      int kt = k >> 5, q = (k >> 3) & 3, j = k & 7;
      Bpkl[(((kt * 4 + q) * 128 + c) << 3) + j] = f2bf(v);
    }
  }
}

__global__ void k_cast(const float* __restrict__ x, ushort* __restrict__ xb, int n4) {
  int i = blockIdx.x * BLK + threadIdx.x;
  if (i < n4) {
    float4 v = ((const float4*)x)[i];
    ushort4 o = { f2bf(v.x), f2bf(v.y), f2bf(v.z), f2bf(v.w) };
    ((ushort4*)xb)[i] = o;
  }
}

// ---------------- MFMA bf16 GEMM: C[nrows,NC] = A[nrows,128] @ B[128,NC] ----------------
// SPLIT: cols 0..127 -> O0 (bf16), 128..255 -> O1 (bf16). else: O0 = bf16(relu(C+bias)).
template<int NC, bool SPLIT>
__global__ __launch_bounds__(256) void k_mgemm(
    const ushort* __restrict__ A, int nrows,
    const ushort* __restrict__ Bpk, const float* __restrict__ bias,
    ushort* __restrict__ O0, ushort* __restrict__ O1) {
  constexpr int NCW = NC / 4;   // cols per wave
  constexpr int NT = NCW / 16;  // 16x16 tiles per wave
  __shared__ ushort Cs[16 * NC];
  const int t = threadIdx.x;
  const int w = t >> 6, l = t & 63;
  const int lr = l & 15, lq = l >> 4;
  const int r0 = blockIdx.x * 16;
  const int ar = min(r0 + lr, nrows - 1);
  const ushort* Ap = A + (size_t)ar * 128 + lq * 8;
  f32x4 acc[NT];
#pragma unroll
  for (int n = 0; n < NT; ++n) acc[n] = f32x4{0.f, 0.f, 0.f, 0.f};
#pragma unroll
  for (int kt = 0; kt < 4; ++kt) {
    short8 af = *(const short8*)(Ap + kt * 32);
    const ushort* bbase = Bpk + ((size_t)((kt * 4 + lq) * NC) + w * NCW + lr) * 8;
#pragma unroll
    for (int n = 0; n < NT; ++n) {
      short8 bf = *(const short8*)(bbase + n * 16 * 8);
      acc[n] = __builtin_amdgcn_mfma_f32_16x16x32_bf16(af, bf, acc[n], 0, 0, 0);
    }
  }
#pragma unroll
  for (int n = 0; n < NT; ++n)
#pragma unroll
    for (int r = 0; r < 4; ++r) {
      int row = lq * 4 + r;             // C/D: col=lane&15, row=(lane>>4)*4+reg
      int col = w * NCW + n * 16 + lr;
      float v = acc[n][r];
      if (!SPLIT) v = fmaxf(v + bias[col], 0.f);
      Cs[row * NC + col] = f2bf(v);
    }
  __syncthreads();
  int row = t >> 4, c16 = t & 15;
  if (r0 + row >= nrows) return;
  if (SPLIT) {
    uint4 v0 = *(const uint4*)(Cs + row * 256 + c16 * 8);
    uint4 v1 = *(const uint4*)(Cs + row * 256 + 128 + c16 * 8);
    *(uint4*)(O0 + (size_t)(r0 + row) * 128 + c16 * 8) = v0;
    *(uint4*)(O1 + (size_t)(r0 + row) * 128 + c16 * 8) = v1;
  } else {
    uint4 v0 = *(const uint4*)(Cs + row * 128 + c16 * 8);
    *(uint4*)(O0 + (size_t)(r0 + row) * 128 + c16 * 8) = v0;
  }
}

// ---------------- fused aggregate + antisym combine (+relu) ----------------
// out = relu( xin + 0.1*tanh( xm + bias + xw*dinv^2 + sum_e xw[src]*norm ) )
template<bool XIN_BF, bool OUT_BF>
__global__ __launch_bounds__(256) void k_aggc(
    const ushort* __restrict__ xwb, const ushort* __restrict__ xmb,
    const float* __restrict__ xinf, const ushort* __restrict__ xinb,
    const float* __restrict__ dinv,
    const int* __restrict__ rowp, const int* __restrict__ csrc,
    const float* __restrict__ enorm, const float* __restrict__ bias,
    float* __restrict__ outf, ushort* __restrict__ outb, int n) {
  int node = blockIdx.x * 4 + (threadIdx.x >> 6);
  if (node >= n) return;
  int l = threadIdx.x & 63;  // features 2l, 2l+1
  float di = dinv[node];
  float dsq = di * di;
  uint su = *(const uint*)(xwb + (size_t)node * 128 + 2 * l);
  float a0 = bflo(su) * dsq, a1 = bfhi(su) * dsq;
  int e0 = rowp[node], e1 = rowp[node + 1];
  int e = e0;
  for (; e + 1 < e1; e += 2) {
    int s0 = csrc[e], s1 = csrc[e + 1];
    float w0 = enorm[e], w1 = enorm[e + 1];
    uint g0 = *(const uint*)(xwb + (size_t)s0 * 128 + 2 * l);
    uint g1 = *(const uint*)(xwb + (size_t)s1 * 128 + 2 * l);
    a0 += bflo(g0) * w0; a1 += bfhi(g0) * w0;
    a0 += bflo(g1) * w1; a1 += bfhi(g1) * w1;
  }
  if (e < e1) {
    int s0 = csrc[e]; float w0 = enorm[e];
    uint g0 = *(const uint*)(xwb + (size_t)s0 * 128 + 2 * l);
    a0 += bflo(g0) * w0; a1 += bfhi(g0) * w0;
  }
  uint mu = *(const uint*)(xmb + (size_t)node * 128 + 2 * l);
  float h0 = a0 + bflo(mu) + bias[2 * l];
  float h1 = a1 + bfhi(mu) + bias[2 * l + 1];
  float x0, x1v;
  if (XIN_BF) {
    uint xu = *(const uint*)(xinb + (size_t)node * 128 + 2 * l);
    x0 = bflo(xu); x1v = bfhi(xu);
  } else {
    float2 xv = *(const float2*)(xinf + (size_t)node * 128 + 2 * l);
    x0 = xv.x; x1v = xv.y;
  }
  float o0 = fmaxf(x0 + EPS_ * tanhf(h0), 0.f);
  float o1 = fmaxf(x1v + EPS_ * tanhf(h1), 0.f);
  if (OUT_BF) {
    ushort2 o = { f2bf(o0), f2bf(o1) };
    *(ushort2*)(outb + (size_t)node * 128 + 2 * l) = o;
  } else {
    float2 o = { o0, o1 };
    *(float2*)(outf + (size_t)node * 128 + 2 * l) = o;
  }
}

// ---------------- fused final linear + log_softmax ----------------
__global__ __launch_bounds__(256) void k_logits(
    const float* __restrict__ X, const float* __restrict__ lw2,
    const float* __restrict__ lb2, float* __restrict__ out, int n) {
  __shared__ float wl[40 * 130];
  __shared__ float bl[40];
  for (int i = threadIdx.x; i < 40 * 128; i += 256) {
    int c = i >> 7, k = i & 127;
    wl[c * 130 + k] = lw2[i];
  }
  if (threadIdx.x < 40) bl[threadIdx.x] = lb2[threadIdx.x];
  __syncthreads();
  int wid = threadIdx.x >> 6, lane = threadIdx.x & 63;
  int row = blockIdx.x * 4 + wid;
  if (row >= n) return;
  const float* xr = X + (size_t)row * 128;
  float v = 0.f;
  if (lane < 40) {
    const float* wr = wl + lane * 130;
#pragma unroll 8
    for (int k = 0; k < 128; ++k) v += xr[k] * wr[k];
    v += bl[lane];
  }
  float m = (lane < 40) ? v : -INFINITY;
  for (int off = 32; off; off >>= 1) m = fmaxf(m, __shfl_xor(m, off));
  float ex = (lane < 40) ? expf(v - m) : 0.f;
  float ssum = ex;
  for (int off = 32; off; off >>= 1) ssum += __shfl_xor(ssum, off);
  float lse = m + logf(ssum);
  if (lane < 40) out[(size_t)row * 40 + lane] = v - lse;
}

// ---------------- launch ----------------
extern "C" void kernel_launch(void* const* d_in, const int* in_sizes, int n_in,
                              void* d_out, int out_size, void* d_ws, size_t ws_size,
                              hipStream_t stream) {
  const float* x   = (const float*)d_in[0];
  const int*   ei  = (const int*)d_in[1];
  const float* W1  = (const float*)d_in[2];
  const float* b1  = (const float*)d_in[3];
  const float* T1  = (const float*)d_in[4];
  const float* W2  = (const float*)d_in[5];
  const float* b2  = (const float*)d_in[6];
  const float* T2  = (const float*)d_in[7];
  const float* lw1 = (const float*)d_in[8];
  const float* lb1 = (const float*)d_in[9];
  const float* lw2 = (const float*)d_in[10];
  const float* lb2 = (const float*)d_in[11];
  const int N = in_sizes[0] / 128;
  const int E = in_sizes[1] / 2;
  const int* src = ei;
  const int* dst = ei + E;

  float* ws = (float*)d_ws;
  size_t o = 0;
  float* dinv = ws;             o += N;
  int* cnt = (int*)(ws + o);    o += N;
  int* rowp = (int*)(ws + o);   o += (size_t)(N + 4);
  int* csrc = (int*)(ws + o);   o += E;
  float* enorm = ws + o;        o += E;
  int* bsum = (int*)(ws + o);   o += 256;
  int* boff = (int*)(ws + o);   o += 256;
  o = (o + 3) & ~(size_t)3;     // 16B align for ushort region
  ushort* us = (ushort*)(ws + o);
  size_t uo = 0;
  ushort* Bpk1 = us + uo;       uo += 32768;
  ushort* Bpk2 = us + uo;       uo += 32768;
  ushort* Bpkl = us + uo;       uo += 16384;
  ushort* xb   = us + uo;       uo += (size_t)N * 128;
  ushort* xwb  = us + uo;       uo += (size_t)N * 128;
  ushort* xmb  = us + uo;       uo += (size_t)N * 128;
  ushort* h1b  = us + uo;       uo += (size_t)N * 128;
  ushort* h2b  = us + uo;       uo += (size_t)N * 128;

  float* outp = (float*)d_out;
  float* x1 = outp + (size_t)N * 40;

  int nb_n = (N + BLK - 1) / BLK;
  int nb_e = (E + BLK - 1) / BLK;
  int nb_r = (N + 15) / 16;

  k_init<<<nb_n, BLK, 0, stream>>>(cnt, N);
  k_count<<<nb_e, BLK, 0, stream>>>(dst, cnt, E);
  k_scan1<<<nb_n, BLK, 0, stream>>>(cnt, rowp, bsum, N);
  k_scan2<<<1, BLK, 0, stream>>>(bsum, boff, nb_n);
  k_scan3<<<nb_n, BLK, 0, stream>>>(boff, rowp, cnt, dinv, N, E);
  k_fill<<<nb_e, BLK, 0, stream>>>(src, dst, rowp, cnt, dinv, csrc, enorm, E);
  k_pack<<<320, BLK, 0, stream>>>(W1, T1, W2, T2, lw1, Bpk1, Bpk2, Bpkl);
  k_cast<<<(N * 32 + BLK - 1) / BLK, BLK, 0, stream>>>(x, xb, N * 32);

  // layer 1: [xw | xm] = xb @ [T1 | M1^T]
  k_mgemm<256, true><<<nb_r, 256, 0, stream>>>(xb, N, Bpk1, nullptr, xwb, xmb);
  k_aggc<false, true><<<(N + 3) / 4, 256, 0, stream>>>(
      xwb, xmb, x, nullptr, dinv, rowp, csrc, enorm, b1, nullptr, h1b, N);
  // linear 1 + relu
  k_mgemm<128, false><<<nb_r, 256, 0, stream>>>(h1b, N, Bpkl, lb1, h2b, nullptr);
  // layer 2
  k_mgemm<256, true><<<nb_r, 256, 0, stream>>>(h2b, N, Bpk2, nullptr, xwb, xmb);
  k_aggc<true, false><<<(N + 3) / 4, 256, 0, stream>>>(
      xwb, xmb, nullptr, h2b, dinv, rowp, csrc, enorm, b2, x1, nullptr, N);
  // linear 2 + log_softmax
  k_logits<<<(N + 3) / 4, 256, 0, stream>>>(x1, lw2, lb2, outp, N);
}

// Round 3
// 255.225 us; speedup vs baseline: 2.4097x; 1.2694x over previous
//
#include <hip/hip_runtime.h>
#include <hip/hip_bf16.h>
#include <math.h>

#define GAMMA_ 0.1f
#define EPS_ 0.1f
constexpr int BLK = 256;

typedef __attribute__((ext_vector_type(8))) short short8;
typedef __attribute__((ext_vector_type(4))) float f32x4;

__device__ inline float bflo(uint u) { union { uint i; float f; } v; v.i = u << 16; return v.f; }
__device__ inline float bfhi(uint u) { union { uint i; float f; } v; v.i = u & 0xffff0000u; return v.f; }
__device__ inline ushort f2bf(float f) {
  union { float f; uint i; } v; v.f = f;
  uint i = v.i;
  return (ushort)((i + 0x7fffu + ((i >> 16) & 1u)) >> 16);  // RNE
}

// ---------------- graph prep ----------------
__global__ void k_init(int* cnt, int n) {
  int i = blockIdx.x * BLK + threadIdx.x;
  if (i < n) cnt[i] = 0;
}

__global__ void k_count(const int* __restrict__ dst, int* cnt, int e) {
  int i = blockIdx.x * BLK + threadIdx.x;
  if (i < e) atomicAdd(&cnt[dst[i]], 1);
}

__global__ void k_scan1(const int* __restrict__ cnt, int* __restrict__ rowp,
                        int* __restrict__ bsum, int n) {
  __shared__ int s[BLK];
  int t = threadIdx.x;
  int i = blockIdx.x * BLK + t;
  int v = (i < n) ? cnt[i] : 0;
  s[t] = v; __syncthreads();
  for (int off = 1; off < BLK; off <<= 1) {
    int u = (t >= off) ? s[t - off] : 0;
    __syncthreads();
    s[t] += u;
    __syncthreads();
  }
  if (i < n) rowp[i] = s[t] - v;
  if (t == BLK - 1) bsum[blockIdx.x] = s[t];
}

__global__ void k_scan2(const int* __restrict__ bsum, int* __restrict__ boff, int nb) {
  __shared__ int s[BLK];
  int t = threadIdx.x;
  int v = (t < nb) ? bsum[t] : 0;
  s[t] = v; __syncthreads();
  for (int off = 1; off < BLK; off <<= 1) {
    int u = (t >= off) ? s[t - off] : 0;
    __syncthreads();
    s[t] += u;
    __syncthreads();
  }
  if (t < nb) boff[t] = s[t] - v;
}

__global__ void k_scan3(const int* __restrict__ boff, int* __restrict__ rowp,
                        int* __restrict__ cnt, float* __restrict__ dinv, int n, int e) {
  int i = blockIdx.x * BLK + threadIdx.x;
  if (i < n) {
    rowp[i] += boff[blockIdx.x];
    dinv[i] = rsqrtf((float)cnt[i] + 1.0f);
    cnt[i] = 0;
    if (i == 0) rowp[n] = e;
  }
}

__global__ void k_fill(const int* __restrict__ src, const int* __restrict__ dst,
                       const int* __restrict__ rowp, int* __restrict__ cnt,
                       const float* __restrict__ dinv,
                       int* __restrict__ csrc, float* __restrict__ enorm, int e) {
  int i = blockIdx.x * BLK + threadIdx.x;
  if (i < e) {
    int d = dst[i], s = src[i];
    int pos = rowp[d] + atomicAdd(&cnt[d], 1);
    csrc[pos] = s;
    enorm[pos] = dinv[s] * dinv[d];
  }
}

// ---------------- weight packing (bf16 MFMA fragment order) ----------------
// Bpk[((kt*4+q)*NC + c)*8 + j] = B[kt*32 + q*8 + j][c]
__global__ void k_pack(const float* __restrict__ W1, const float* __restrict__ T1,
                       const float* __restrict__ W2, const float* __restrict__ T2,
                       const float* __restrict__ lw1, const float* __restrict__ lw2,
                       ushort* __restrict__ Bpk1, ushort* __restrict__ Bpk2,
                       ushort* __restrict__ Bpkl, ushort* __restrict__ Bpk2l) {
  int idx = blockIdx.x * BLK + threadIdx.x;
  if (idx < 65536) {
    int which = idx >> 15;
    int e = idx & 32767;
    int k = e >> 8, c = e & 255;
    const float* W = which ? W2 : W1;
    const float* T = which ? T2 : T1;
    float v;
    if (c < 128) {
      v = T[k * 128 + c];
    } else {
      int cc = c - 128;  // (M^T)[k][cc] = M[cc][k] = W[cc][k] - W[k][cc] - g*delta
      v = W[cc * 128 + k] - W[k * 128 + cc] - ((cc == k) ? GAMMA_ : 0.f);
    }
    int kt = k >> 5, q = (k >> 3) & 3, j = k & 7;
    ushort* B = which ? Bpk2 : Bpk1;
    B[(((kt * 4 + q) * 256 + c) << 3) + j] = f2bf(v);
  } else if (idx < 81920) {
    int e = idx - 65536;
    int k = e >> 7, c = e & 127;
    float v = lw1[c * 128 + k];  // lw1^T[k][c]
    int kt = k >> 5, q = (k >> 3) & 3, j = k & 7;
    Bpkl[(((kt * 4 + q) * 128 + c) << 3) + j] = f2bf(v);
  } else {
    int e = idx - 81920;       // 128*48 = 6144 entries
    if (e < 6144) {
      int k = e / 48, c = e - k * 48;
      float v = (c < 40) ? lw2[c * 128 + k] : 0.f;  // lw2^T[k][c], zero-padded
      int kt = k >> 5, q = (k >> 3) & 3, j = k & 7;
      Bpk2l[(((kt * 4 + q) * 48 + c) << 3) + j] = f2bf(v);
    }
  }
}

__global__ void k_cast(const float* __restrict__ x, ushort* __restrict__ xb, int n4) {
  int i = blockIdx.x * BLK + threadIdx.x;
  if (i < n4) {
    float4 v = ((const float4*)x)[i];
    ushort4 o = { f2bf(v.x), f2bf(v.y), f2bf(v.z), f2bf(v.w) };
    ((ushort4*)xb)[i] = o;
  }
}

// ---------------- MFMA bf16 GEMM: C[nrows,NC] = A[nrows,128] @ B[128,NC] ----------------
template<int NC, bool SPLIT>
__global__ __launch_bounds__(256) void k_mgemm(
    const ushort* __restrict__ A, int nrows,
    const ushort* __restrict__ Bpk, const float* __restrict__ bias,
    ushort* __restrict__ O0, ushort* __restrict__ O1) {
  constexpr int NCW = NC / 4;   // cols per wave
  constexpr int NT = NCW / 16;  // 16x16 tiles per wave
  __shared__ ushort Cs[16 * NC];
  const int t = threadIdx.x;
  const int w = t >> 6, l = t & 63;
  const int lr = l & 15, lq = l >> 4;
  const int r0 = blockIdx.x * 16;
  const int ar = min(r0 + lr, nrows - 1);
  const ushort* Ap = A + (size_t)ar * 128 + lq * 8;
  f32x4 acc[NT];
#pragma unroll
  for (int n = 0; n < NT; ++n) acc[n] = f32x4{0.f, 0.f, 0.f, 0.f};
#pragma unroll
  for (int kt = 0; kt < 4; ++kt) {
    short8 af = *(const short8*)(Ap + kt * 32);
    const ushort* bbase = Bpk + ((size_t)((kt * 4 + lq) * NC) + w * NCW + lr) * 8;
#pragma unroll
    for (int n = 0; n < NT; ++n) {
      short8 bf = *(const short8*)(bbase + n * 16 * 8);
      acc[n] = __builtin_amdgcn_mfma_f32_16x16x32_bf16(af, bf, acc[n], 0, 0, 0);
    }
  }
#pragma unroll
  for (int n = 0; n < NT; ++n)
#pragma unroll
    for (int r = 0; r < 4; ++r) {
      int row = lq * 4 + r;             // C/D: col=lane&15, row=(lane>>4)*4+reg
      int col = w * NCW + n * 16 + lr;
      float v = acc[n][r];
      if (!SPLIT) v = fmaxf(v + bias[col], 0.f);
      Cs[row * NC + col] = f2bf(v);
    }
  __syncthreads();
  int row = t >> 4, c16 = t & 15;
  if (r0 + row >= nrows) return;
  if (SPLIT) {
    uint4 v0 = *(const uint4*)(Cs + row * 256 + c16 * 8);
    uint4 v1 = *(const uint4*)(Cs + row * 256 + 128 + c16 * 8);
    *(uint4*)(O0 + (size_t)(r0 + row) * 128 + c16 * 8) = v0;
    *(uint4*)(O1 + (size_t)(r0 + row) * 128 + c16 * 8) = v1;
  } else {
    uint4 v0 = *(const uint4*)(Cs + row * 128 + c16 * 8);
    *(uint4*)(O0 + (size_t)(r0 + row) * 128 + c16 * 8) = v0;
  }
}

// ---------------- fused aggregate + antisym combine (+relu) ----------------
template<bool XIN_BF, bool OUT_BF>
__global__ __launch_bounds__(256) void k_aggc(
    const ushort* __restrict__ xwb, const ushort* __restrict__ xmb,
    const float* __restrict__ xinf, const ushort* __restrict__ xinb,
    const float* __restrict__ dinv,
    const int* __restrict__ rowp, const int* __restrict__ csrc,
    const float* __restrict__ enorm, const float* __restrict__ bias,
    float* __restrict__ outf, ushort* __restrict__ outb, int n) {
  int node = blockIdx.x * 4 + (threadIdx.x >> 6);
  if (node >= n) return;
  int l = threadIdx.x & 63;  // features 2l, 2l+1
  float di = dinv[node];
  float dsq = di * di;
  uint su = *(const uint*)(xwb + (size_t)node * 128 + 2 * l);
  float a0 = bflo(su) * dsq, a1 = bfhi(su) * dsq;
  int e0 = rowp[node], e1 = rowp[node + 1];
  int e = e0;
  for (; e + 3 < e1; e += 4) {
    int s0 = csrc[e], s1 = csrc[e + 1], s2 = csrc[e + 2], s3 = csrc[e + 3];
    float w0 = enorm[e], w1 = enorm[e + 1], w2 = enorm[e + 2], w3 = enorm[e + 3];
    uint g0 = *(const uint*)(xwb + (size_t)s0 * 128 + 2 * l);
    uint g1 = *(const uint*)(xwb + (size_t)s1 * 128 + 2 * l);
    uint g2 = *(const uint*)(xwb + (size_t)s2 * 128 + 2 * l);
    uint g3 = *(const uint*)(xwb + (size_t)s3 * 128 + 2 * l);
    a0 += bflo(g0) * w0; a1 += bfhi(g0) * w0;
    a0 += bflo(g1) * w1; a1 += bfhi(g1) * w1;
    a0 += bflo(g2) * w2; a1 += bfhi(g2) * w2;
    a0 += bflo(g3) * w3; a1 += bfhi(g3) * w3;
  }
  for (; e < e1; ++e) {
    int s0 = csrc[e]; float w0 = enorm[e];
    uint g0 = *(const uint*)(xwb + (size_t)s0 * 128 + 2 * l);
    a0 += bflo(g0) * w0; a1 += bfhi(g0) * w0;
  }
  uint mu = *(const uint*)(xmb + (size_t)node * 128 + 2 * l);
  float h0 = a0 + bflo(mu) + bias[2 * l];
  float h1 = a1 + bfhi(mu) + bias[2 * l + 1];
  float x0, x1v;
  if (XIN_BF) {
    uint xu = *(const uint*)(xinb + (size_t)node * 128 + 2 * l);
    x0 = bflo(xu); x1v = bfhi(xu);
  } else {
    float2 xv = *(const float2*)(xinf + (size_t)node * 128 + 2 * l);
    x0 = xv.x; x1v = xv.y;
  }
  float o0 = fmaxf(x0 + EPS_ * tanhf(h0), 0.f);
  float o1 = fmaxf(x1v + EPS_ * tanhf(h1), 0.f);
  if (OUT_BF) {
    ushort2 o = { f2bf(o0), f2bf(o1) };
    *(ushort2*)(outb + (size_t)node * 128 + 2 * l) = o;
  } else {
    float2 o = { o0, o1 };
    *(float2*)(outf + (size_t)node * 128 + 2 * l) = o;
  }
}

// ---------------- fused final linear (MFMA) + log_softmax ----------------
// X fp32 [n,128]; Bpk packed bf16 [128,48] (cols 40..47 zero); out [n,40]
__global__ __launch_bounds__(256) void k_logits2(
    const float* __restrict__ X, const ushort* __restrict__ Bpk,
    const float* __restrict__ lb2, float* __restrict__ out, int n) {
  __shared__ float Ls[64 * 49];
  __shared__ float bl[48];
  const int t = threadIdx.x;
  if (t < 48) bl[t] = (t < 40) ? lb2[t] : 0.f;
  const int w = t >> 6, l = t & 63;
  const int lr = l & 15, lq = l >> 4;
  const int r0 = blockIdx.x * 64;
  const int ar = min(r0 + w * 16 + lr, n - 1);
  const float* Ap = X + (size_t)ar * 128 + lq * 8;
  f32x4 acc[3];
#pragma unroll
  for (int nn = 0; nn < 3; ++nn) acc[nn] = f32x4{0.f, 0.f, 0.f, 0.f};
#pragma unroll
  for (int kt = 0; kt < 4; ++kt) {
    float4 xa = *(const float4*)(Ap + kt * 32);
    float4 xc = *(const float4*)(Ap + kt * 32 + 4);
    short8 af;
    af[0] = (short)f2bf(xa.x); af[1] = (short)f2bf(xa.y);
    af[2] = (short)f2bf(xa.z); af[3] = (short)f2bf(xa.w);
    af[4] = (short)f2bf(xc.x); af[5] = (short)f2bf(xc.y);
    af[6] = (short)f2bf(xc.z); af[7] = (short)f2bf(xc.w);
    const ushort* bbase = Bpk + ((size_t)((kt * 4 + lq) * 48) + lr) * 8;
#pragma unroll
    for (int nn = 0; nn < 3; ++nn) {
      short8 bf = *(const short8*)(bbase + nn * 16 * 8);
      acc[nn] = __builtin_amdgcn_mfma_f32_16x16x32_bf16(af, bf, acc[nn], 0, 0, 0);
    }
  }
  __syncthreads();  // bl ready
#pragma unroll
  for (int nn = 0; nn < 3; ++nn)
#pragma unroll
    for (int r = 0; r < 4; ++r) {
      int row = w * 16 + lq * 4 + r;
      int col = nn * 16 + lr;
      Ls[row * 49 + col] = acc[nn][r] + bl[col];
    }
  __syncthreads();
  int row = t >> 2, q = t & 3;
  if (r0 + row >= n) return;
  const float* Lr = Ls + row * 49 + q * 10;
  float m = -1e30f;
#pragma unroll
  for (int c = 0; c < 10; ++c) m = fmaxf(m, Lr[c]);
  m = fmaxf(m, __shfl_xor(m, 1));
  m = fmaxf(m, __shfl_xor(m, 2));
  float s = 0.f;
#pragma unroll
  for (int c = 0; c < 10; ++c) s += expf(Lr[c] - m);
  s += __shfl_xor(s, 1);
  s += __shfl_xor(s, 2);
  float lse = m + logf(s);
  float* Or = out + (size_t)(r0 + row) * 40 + q * 10;
#pragma unroll
  for (int c = 0; c < 10; ++c) Or[c] = Lr[c] - lse;
}

// ---------------- launch ----------------
extern "C" void kernel_launch(void* const* d_in, const int* in_sizes, int n_in,
                              void* d_out, int out_size, void* d_ws, size_t ws_size,
                              hipStream_t stream) {
  const float* x   = (const float*)d_in[0];
  const int*   ei  = (const int*)d_in[1];
  const float* W1  = (const float*)d_in[2];
  const float* b1  = (const float*)d_in[3];
  const float* T1  = (const float*)d_in[4];
  const float* W2  = (const float*)d_in[5];
  const float* b2  = (const float*)d_in[6];
  const float* T2  = (const float*)d_in[7];
  const float* lw1 = (const float*)d_in[8];
  const float* lb1 = (const float*)d_in[9];
  const float* lw2 = (const float*)d_in[10];
  const float* lb2 = (const float*)d_in[11];
  const int N = in_sizes[0] / 128;
  const int E = in_sizes[1] / 2;
  const int* src = ei;
  const int* dst = ei + E;

  float* ws = (float*)d_ws;
  size_t o = 0;
  float* dinv = ws;             o += N;
  int* cnt = (int*)(ws + o);    o += N;
  int* rowp = (int*)(ws + o);   o += (size_t)(N + 4);
  int* csrc = (int*)(ws + o);   o += E;
  float* enorm = ws + o;        o += E;
  int* bsum = (int*)(ws + o);   o += 256;
  int* boff = (int*)(ws + o);   o += 256;
  o = (o + 3) & ~(size_t)3;     // 16B align for ushort region
  ushort* us = (ushort*)(ws + o);
  size_t uo = 0;
  ushort* Bpk1 = us + uo;       uo += 32768;
  ushort* Bpk2 = us + uo;       uo += 32768;
  ushort* Bpkl = us + uo;       uo += 16384;
  ushort* Bpk2l = us + uo;      uo += 6144;
  ushort* xb   = us + uo;       uo += (size_t)N * 128;
  ushort* xwb  = us + uo;       uo += (size_t)N * 128;
  ushort* xmb  = us + uo;       uo += (size_t)N * 128;
  ushort* h1b  = us + uo;       uo += (size_t)N * 128;
  ushort* h2b  = us + uo;       uo += (size_t)N * 128;

  float* outp = (float*)d_out;
  float* x1 = outp + (size_t)N * 40;

  int nb_n = (N + BLK - 1) / BLK;
  int nb_e = (E + BLK - 1) / BLK;
  int nb_r = (N + 15) / 16;

  k_init<<<nb_n, BLK, 0, stream>>>(cnt, N);
  k_count<<<nb_e, BLK, 0, stream>>>(dst, cnt, E);
  k_scan1<<<nb_n, BLK, 0, stream>>>(cnt, rowp, bsum, N);
  k_scan2<<<1, BLK, 0, stream>>>(bsum, boff, nb_n);
  k_scan3<<<nb_n, BLK, 0, stream>>>(boff, rowp, cnt, dinv, N, E);
  k_fill<<<nb_e, BLK, 0, stream>>>(src, dst, rowp, cnt, dinv, csrc, enorm, E);
  k_pack<<<344, BLK, 0, stream>>>(W1, T1, W2, T2, lw1, lw2, Bpk1, Bpk2, Bpkl, Bpk2l);
  k_cast<<<(N * 32 + BLK - 1) / BLK, BLK, 0, stream>>>(x, xb, N * 32);

  // layer 1: [xw | xm] = xb @ [T1 | M1^T]
  k_mgemm<256, true><<<nb_r, 256, 0, stream>>>(xb, N, Bpk1, nullptr, xwb, xmb);
  k_aggc<false, true><<<(N + 3) / 4, 256, 0, stream>>>(
      xwb, xmb, x, nullptr, dinv, rowp, csrc, enorm, b1, nullptr, h1b, N);
  // linear 1 + relu
  k_mgemm<128, false><<<nb_r, 256, 0, stream>>>(h1b, N, Bpkl, lb1, h2b, nullptr);
  // layer 2
  k_mgemm<256, true><<<nb_r, 256, 0, stream>>>(h2b, N, Bpk2, nullptr, xwb, xmb);
  k_aggc<true, false><<<(N + 3) / 4, 256, 0, stream>>>(
      xwb, xmb, nullptr, h2b, dinv, rowp, csrc, enorm, b2, x1, nullptr, N);
  // linear 2 + log_softmax (MFMA)
  k_logits2<<<(N + 63) / 64, 256, 0, stream>>>(x1, Bpk2l, lb2, outp, N);
}

// Round 4
// 224.363 us; speedup vs baseline: 2.7411x; 1.1376x over previous
//
#include <hip/hip_runtime.h>
#include <hip/hip_bf16.h>
#include <math.h>

#define GAMMA_ 0.1f
#define EPS_ 0.1f
constexpr int BLK = 256;

typedef __attribute__((ext_vector_type(8))) short short8;
typedef __attribute__((ext_vector_type(4))) float f32x4;

__device__ inline float bflo(uint u) { union { uint i; float f; } v; v.i = u << 16; return v.f; }
__device__ inline float bfhi(uint u) { union { uint i; float f; } v; v.i = u & 0xffff0000u; return v.f; }
__device__ inline ushort f2bf(float f) {
  union { float f; uint i; } v; v.f = f;
  uint i = v.i;
  return (ushort)((i + 0x7fffu + ((i >> 16) & 1u)) >> 16);  // RNE
}

// ---------------- graph prep ----------------
__global__ void k_init(int* cnt, int n) {
  int i = blockIdx.x * BLK + threadIdx.x;
  if (i < n) cnt[i] = 0;
}

// count in-degree AND record each edge's rank within its dst bucket
__global__ void k_count(const int* __restrict__ dst, int* cnt,
                        int* __restrict__ rank, int e) {
  int i = blockIdx.x * BLK + threadIdx.x;
  if (i < e) rank[i] = atomicAdd(&cnt[dst[i]], 1);
}

__global__ void k_scan1(const int* __restrict__ cnt, int* __restrict__ rowp,
                        int* __restrict__ bsum, int n) {
  __shared__ int s[BLK];
  int t = threadIdx.x;
  int i = blockIdx.x * BLK + t;
  int v = (i < n) ? cnt[i] : 0;
  s[t] = v; __syncthreads();
  for (int off = 1; off < BLK; off <<= 1) {
    int u = (t >= off) ? s[t - off] : 0;
    __syncthreads();
    s[t] += u;
    __syncthreads();
  }
  if (i < n) rowp[i] = s[t] - v;
  if (t == BLK - 1) bsum[blockIdx.x] = s[t];
}

__global__ void k_scan2(const int* __restrict__ bsum, int* __restrict__ boff, int nb) {
  __shared__ int s[BLK];
  int t = threadIdx.x;
  int v = (t < nb) ? bsum[t] : 0;
  s[t] = v; __syncthreads();
  for (int off = 1; off < BLK; off <<= 1) {
    int u = (t >= off) ? s[t - off] : 0;
    __syncthreads();
    s[t] += u;
    __syncthreads();
  }
  if (t < nb) boff[t] = s[t] - v;
}

__global__ void k_scan3(const int* __restrict__ boff, int* __restrict__ rowp,
                        const int* __restrict__ cnt, float* __restrict__ dinv,
                        int n, int e) {
  int i = blockIdx.x * BLK + threadIdx.x;
  if (i < n) {
    rowp[i] += boff[blockIdx.x];
    dinv[i] = rsqrtf((float)cnt[i] + 1.0f);
    if (i == 0) rowp[n] = e;
  }
}

// scatter src into CSR slot (no atomics: rank precomputed)
__global__ void k_fill(const int* __restrict__ src, const int* __restrict__ dst,
                       const int* __restrict__ rowp, const int* __restrict__ rank,
                       int* __restrict__ csrc, int e) {
  int i = blockIdx.x * BLK + threadIdx.x;
  if (i < e) {
    int d = dst[i];
    csrc[rowp[d] + rank[i]] = src[i];
  }
}

// ---------------- weight packing (bf16 MFMA fragment order) ----------------
// Bpk[((kt*4+q)*NC + c)*8 + j] = B[kt*32 + q*8 + j][c]
__global__ void k_pack(const float* __restrict__ W1, const float* __restrict__ T1,
                       const float* __restrict__ W2, const float* __restrict__ T2,
                       const float* __restrict__ lw1, const float* __restrict__ lw2,
                       ushort* __restrict__ Bpk1, ushort* __restrict__ Bpk2,
                       ushort* __restrict__ Bpkl, ushort* __restrict__ Bpk2l) {
  int idx = blockIdx.x * BLK + threadIdx.x;
  if (idx < 65536) {
    int which = idx >> 15;
    int e = idx & 32767;
    int k = e >> 8, c = e & 255;
    const float* W = which ? W2 : W1;
    const float* T = which ? T2 : T1;
    float v;
    if (c < 128) {
      v = T[k * 128 + c];
    } else {
      int cc = c - 128;  // (M^T)[k][cc] = M[cc][k] = W[cc][k] - W[k][cc] - g*delta
      v = W[cc * 128 + k] - W[k * 128 + cc] - ((cc == k) ? GAMMA_ : 0.f);
    }
    int kt = k >> 5, q = (k >> 3) & 3, j = k & 7;
    ushort* B = which ? Bpk2 : Bpk1;
    B[(((kt * 4 + q) * 256 + c) << 3) + j] = f2bf(v);
  } else if (idx < 81920) {
    int e = idx - 65536;
    int k = e >> 7, c = e & 127;
    float v = lw1[c * 128 + k];  // lw1^T[k][c]
    int kt = k >> 5, q = (k >> 3) & 3, j = k & 7;
    Bpkl[(((kt * 4 + q) * 128 + c) << 3) + j] = f2bf(v);
  } else {
    int e = idx - 81920;       // 128*48 = 6144 entries
    if (e < 6144) {
      int k = e / 48, c = e - k * 48;
      float v = (c < 40) ? lw2[c * 128 + k] : 0.f;  // lw2^T[k][c], zero-padded
      int kt = k >> 5, q = (k >> 3) & 3, j = k & 7;
      Bpk2l[(((kt * 4 + q) * 48 + c) << 3) + j] = f2bf(v);
    }
  }
}

// ---------------- MFMA bf16 GEMM: C[nrows,NC] = A[nrows,128] @ B[128,NC] ----------------
// FP32A: A is fp32 (converted in-register). SPLIT: cols 0..127 -> O0 scaled by dinv[row],
// cols 128..255 -> O1. !SPLIT: O0 = bf16(relu(C+bias)).
template<int NC, bool SPLIT, bool FP32A>
__global__ __launch_bounds__(256) void k_mgemm(
    const void* __restrict__ Av, int nrows,
    const ushort* __restrict__ Bpk, const float* __restrict__ bias,
    const float* __restrict__ dinv,
    ushort* __restrict__ O0, ushort* __restrict__ O1) {
  constexpr int NCW = NC / 4;   // cols per wave
  constexpr int NT = NCW / 16;  // 16x16 tiles per wave
  __shared__ ushort Cs[16 * NC];
  const int t = threadIdx.x;
  const int w = t >> 6, l = t & 63;
  const int lr = l & 15, lq = l >> 4;
  const int r0 = blockIdx.x * 16;
  const int ar = min(r0 + lr, nrows - 1);
  f32x4 acc[NT];
#pragma unroll
  for (int n = 0; n < NT; ++n) acc[n] = f32x4{0.f, 0.f, 0.f, 0.f};
#pragma unroll
  for (int kt = 0; kt < 4; ++kt) {
    short8 af;
    if (FP32A) {
      const float* Ap = (const float*)Av + (size_t)ar * 128 + lq * 8 + kt * 32;
      float4 xa = *(const float4*)(Ap);
      float4 xc = *(const float4*)(Ap + 4);
      af[0] = (short)f2bf(xa.x); af[1] = (short)f2bf(xa.y);
      af[2] = (short)f2bf(xa.z); af[3] = (short)f2bf(xa.w);
      af[4] = (short)f2bf(xc.x); af[5] = (short)f2bf(xc.y);
      af[6] = (short)f2bf(xc.z); af[7] = (short)f2bf(xc.w);
    } else {
      const ushort* Ap = (const ushort*)Av + (size_t)ar * 128 + lq * 8 + kt * 32;
      af = *(const short8*)Ap;
    }
    const ushort* bbase = Bpk + ((size_t)((kt * 4 + lq) * NC) + w * NCW + lr) * 8;
#pragma unroll
    for (int n = 0; n < NT; ++n) {
      short8 bf = *(const short8*)(bbase + n * 16 * 8);
      acc[n] = __builtin_amdgcn_mfma_f32_16x16x32_bf16(af, bf, acc[n], 0, 0, 0);
    }
  }
#pragma unroll
  for (int n = 0; n < NT; ++n)
#pragma unroll
    for (int r = 0; r < 4; ++r) {
      int row = lq * 4 + r;             // C/D: col=lane&15, row=(lane>>4)*4+reg
      int col = w * NCW + n * 16 + lr;
      float v = acc[n][r];
      if (SPLIT) {
        if (col < 128) v *= dinv[min(r0 + row, nrows - 1)];  // pre-scale xw by dinv
      } else {
        v = fmaxf(v + bias[col], 0.f);
      }
      Cs[row * NC + col] = f2bf(v);
    }
  __syncthreads();
  int row = t >> 4, c16 = t & 15;
  if (r0 + row >= nrows) return;
  if (SPLIT) {
    uint4 v0 = *(const uint4*)(Cs + row * 256 + c16 * 8);
    uint4 v1 = *(const uint4*)(Cs + row * 256 + 128 + c16 * 8);
    *(uint4*)(O0 + (size_t)(r0 + row) * 128 + c16 * 8) = v0;
    *(uint4*)(O1 + (size_t)(r0 + row) * 128 + c16 * 8) = v1;
  } else {
    uint4 v0 = *(const uint4*)(Cs + row * 128 + c16 * 8);
    *(uint4*)(O0 + (size_t)(r0 + row) * 128 + c16 * 8) = v0;
  }
}

// ---------------- fused aggregate + antisym combine (+relu) ----------------
// xws = bf16(xw*dinv) gather table.
// h = dinv[node]*(xws[node] + sum_e xws[src]) + xm[node] + bias
// out = relu( xin + 0.1*tanh(h) )
template<bool XIN_BF, bool OUT_BF>
__global__ __launch_bounds__(256) void k_aggc(
    const ushort* __restrict__ xws, const ushort* __restrict__ xmb,
    const float* __restrict__ xinf, const ushort* __restrict__ xinb,
    const float* __restrict__ dinv,
    const int* __restrict__ rowp, const int* __restrict__ csrc,
    const float* __restrict__ bias,
    float* __restrict__ outf, ushort* __restrict__ outb, int n) {
  int node = blockIdx.x * 4 + (threadIdx.x >> 6);
  if (node >= n) return;
  int l = threadIdx.x & 63;  // features 2l, 2l+1
  uint su = *(const uint*)(xws + (size_t)node * 128 + 2 * l);
  float a0 = bflo(su), a1 = bfhi(su);
  int e0 = rowp[node], e1 = rowp[node + 1];
  int e = e0;
  for (; e + 7 < e1; e += 8) {
    int s[8];
#pragma unroll
    for (int u = 0; u < 8; ++u) s[u] = csrc[e + u];
    uint g[8];
#pragma unroll
    for (int u = 0; u < 8; ++u)
      g[u] = *(const uint*)(xws + (size_t)s[u] * 128 + 2 * l);
#pragma unroll
    for (int u = 0; u < 8; ++u) { a0 += bflo(g[u]); a1 += bfhi(g[u]); }
  }
  if (e + 3 < e1) {
    int s[4];
#pragma unroll
    for (int u = 0; u < 4; ++u) s[u] = csrc[e + u];
    uint g[4];
#pragma unroll
    for (int u = 0; u < 4; ++u)
      g[u] = *(const uint*)(xws + (size_t)s[u] * 128 + 2 * l);
#pragma unroll
    for (int u = 0; u < 4; ++u) { a0 += bflo(g[u]); a1 += bfhi(g[u]); }
    e += 4;
  }
  for (; e < e1; ++e) {
    uint g0 = *(const uint*)(xws + (size_t)csrc[e] * 128 + 2 * l);
    a0 += bflo(g0); a1 += bfhi(g0);
  }
  float di = dinv[node];
  uint mu = *(const uint*)(xmb + (size_t)node * 128 + 2 * l);
  float h0 = a0 * di + bflo(mu) + bias[2 * l];
  float h1 = a1 * di + bfhi(mu) + bias[2 * l + 1];
  float x0, x1v;
  if (XIN_BF) {
    uint xu = *(const uint*)(xinb + (size_t)node * 128 + 2 * l);
    x0 = bflo(xu); x1v = bfhi(xu);
  } else {
    float2 xv = *(const float2*)(xinf + (size_t)node * 128 + 2 * l);
    x0 = xv.x; x1v = xv.y;
  }
  float o0 = fmaxf(x0 + EPS_ * tanhf(h0), 0.f);
  float o1 = fmaxf(x1v + EPS_ * tanhf(h1), 0.f);
  if (OUT_BF) {
    ushort2 o = { f2bf(o0), f2bf(o1) };
    *(ushort2*)(outb + (size_t)node * 128 + 2 * l) = o;
  } else {
    float2 o = { o0, o1 };
    *(float2*)(outf + (size_t)node * 128 + 2 * l) = o;
  }
}

// ---------------- fused final linear (MFMA) + log_softmax ----------------
__global__ __launch_bounds__(256) void k_logits2(
    const float* __restrict__ X, const ushort* __restrict__ Bpk,
    const float* __restrict__ lb2, float* __restrict__ out, int n) {
  __shared__ float Ls[64 * 49];
  __shared__ float bl[48];
  const int t = threadIdx.x;
  if (t < 48) bl[t] = (t < 40) ? lb2[t] : 0.f;
  const int w = t >> 6, l = t & 63;
  const int lr = l & 15, lq = l >> 4;
  const int r0 = blockIdx.x * 64;
  const int ar = min(r0 + w * 16 + lr, n - 1);
  const float* Ap = X + (size_t)ar * 128 + lq * 8;
  f32x4 acc[3];
#pragma unroll
  for (int nn = 0; nn < 3; ++nn) acc[nn] = f32x4{0.f, 0.f, 0.f, 0.f};
#pragma unroll
  for (int kt = 0; kt < 4; ++kt) {
    float4 xa = *(const float4*)(Ap + kt * 32);
    float4 xc = *(const float4*)(Ap + kt * 32 + 4);
    short8 af;
    af[0] = (short)f2bf(xa.x); af[1] = (short)f2bf(xa.y);
    af[2] = (short)f2bf(xa.z); af[3] = (short)f2bf(xa.w);
    af[4] = (short)f2bf(xc.x); af[5] = (short)f2bf(xc.y);
    af[6] = (short)f2bf(xc.z); af[7] = (short)f2bf(xc.w);
    const ushort* bbase = Bpk + ((size_t)((kt * 4 + lq) * 48) + lr) * 8;
#pragma unroll
    for (int nn = 0; nn < 3; ++nn) {
      short8 bf = *(const short8*)(bbase + nn * 16 * 8);
      acc[nn] = __builtin_amdgcn_mfma_f32_16x16x32_bf16(af, bf, acc[nn], 0, 0, 0);
    }
  }
  __syncthreads();  // bl ready
#pragma unroll
  for (int nn = 0; nn < 3; ++nn)
#pragma unroll
    for (int r = 0; r < 4; ++r) {
      int row = w * 16 + lq * 4 + r;
      int col = nn * 16 + lr;
      Ls[row * 49 + col] = acc[nn][r] + bl[col];
    }
  __syncthreads();
  int row = t >> 2, q = t & 3;
  if (r0 + row >= n) return;
  const float* Lr = Ls + row * 49 + q * 10;
  float m = -1e30f;
#pragma unroll
  for (int c = 0; c < 10; ++c) m = fmaxf(m, Lr[c]);
  m = fmaxf(m, __shfl_xor(m, 1));
  m = fmaxf(m, __shfl_xor(m, 2));
  float s = 0.f;
#pragma unroll
  for (int c = 0; c < 10; ++c) s += expf(Lr[c] - m);
  s += __shfl_xor(s, 1);
  s += __shfl_xor(s, 2);
  float lse = m + logf(s);
  float* Or = out + (size_t)(r0 + row) * 40 + q * 10;
#pragma unroll
  for (int c = 0; c < 10; ++c) Or[c] = Lr[c] - lse;
}

// ---------------- launch ----------------
extern "C" void kernel_launch(void* const* d_in, const int* in_sizes, int n_in,
                              void* d_out, int out_size, void* d_ws, size_t ws_size,
                              hipStream_t stream) {
  const float* x   = (const float*)d_in[0];
  const int*   ei  = (const int*)d_in[1];
  const float* W1  = (const float*)d_in[2];
  const float* b1  = (const float*)d_in[3];
  const float* T1  = (const float*)d_in[4];
  const float* W2  = (const float*)d_in[5];
  const float* b2  = (const float*)d_in[6];
  const float* T2  = (const float*)d_in[7];
  const float* lw1 = (const float*)d_in[8];
  const float* lb1 = (const float*)d_in[9];
  const float* lw2 = (const float*)d_in[10];
  const float* lb2 = (const float*)d_in[11];
  const int N = in_sizes[0] / 128;
  const int E = in_sizes[1] / 2;
  const int* src = ei;
  const int* dst = ei + E;

  float* ws = (float*)d_ws;
  size_t o = 0;
  float* dinv = ws;             o += N;
  int* cnt = (int*)(ws + o);    o += N;
  int* rowp = (int*)(ws + o);   o += (size_t)(N + 4);
  int* csrc = (int*)(ws + o);   o += E;
  int* rank = (int*)(ws + o);   o += E;
  int* bsum = (int*)(ws + o);   o += 256;
  int* boff = (int*)(ws + o);   o += 256;
  o = (o + 3) & ~(size_t)3;     // 16B align for ushort region
  ushort* us = (ushort*)(ws + o);
  size_t uo = 0;
  ushort* Bpk1 = us + uo;       uo += 32768;
  ushort* Bpk2 = us + uo;       uo += 32768;
  ushort* Bpkl = us + uo;       uo += 16384;
  ushort* Bpk2l = us + uo;      uo += 6144;
  ushort* xwb  = us + uo;       uo += (size_t)N * 128;
  ushort* xmb  = us + uo;       uo += (size_t)N * 128;
  ushort* h1b  = us + uo;       uo += (size_t)N * 128;
  ushort* h2b  = us + uo;       uo += (size_t)N * 128;

  float* outp = (float*)d_out;
  float* x1 = outp + (size_t)N * 40;

  int nb_n = (N + BLK - 1) / BLK;
  int nb_e = (E + BLK - 1) / BLK;
  int nb_r = (N + 15) / 16;

  k_init<<<nb_n, BLK, 0, stream>>>(cnt, N);
  k_count<<<nb_e, BLK, 0, stream>>>(dst, cnt, rank, E);
  k_scan1<<<nb_n, BLK, 0, stream>>>(cnt, rowp, bsum, N);
  k_scan2<<<1, BLK, 0, stream>>>(bsum, boff, nb_n);
  k_scan3<<<nb_n, BLK, 0, stream>>>(boff, rowp, cnt, dinv, N, E);
  k_fill<<<nb_e, BLK, 0, stream>>>(src, dst, rowp, rank, csrc, E);
  k_pack<<<344, BLK, 0, stream>>>(W1, T1, W2, T2, lw1, lw2, Bpk1, Bpk2, Bpkl, Bpk2l);

  // layer 1: [xws | xm] = x @ [T1 | M1^T]  (fp32 A, xw scaled by dinv in epilogue)
  k_mgemm<256, true, true><<<nb_r, 256, 0, stream>>>(x, N, Bpk1, nullptr, dinv, xwb, xmb);
  k_aggc<false, true><<<(N + 3) / 4, 256, 0, stream>>>(
      xwb, xmb, x, nullptr, dinv, rowp, csrc, b1, nullptr, h1b, N);
  // linear 1 + relu
  k_mgemm<128, false, false><<<nb_r, 256, 0, stream>>>(h1b, N, Bpkl, lb1, nullptr, h2b, nullptr);
  // layer 2
  k_mgemm<256, true, false><<<nb_r, 256, 0, stream>>>(h2b, N, Bpk2, nullptr, dinv, xwb, xmb);
  k_aggc<true, false><<<(N + 3) / 4, 256, 0, stream>>>(
      xwb, xmb, nullptr, h2b, dinv, rowp, csrc, b2, x1, nullptr, N);
  // linear 2 + log_softmax (MFMA)
  k_logits2<<<(N + 63) / 64, 256, 0, stream>>>(x1, Bpk2l, lb2, outp, N);
}

// Round 6
// 192.775 us; speedup vs baseline: 3.1903x; 1.1639x over previous
//
#include <hip/hip_runtime.h>
#include <hip/hip_bf16.h>
#include <math.h>

#define GAMMA_ 0.1f
#define EPS_ 0.1f
constexpr int BLK = 256;

typedef __attribute__((ext_vector_type(8))) short short8;
typedef __attribute__((ext_vector_type(4))) float f32x4;
typedef __attribute__((ext_vector_type(2))) float f32x2v;
typedef unsigned char u8;

__device__ inline float bflo(uint u) { union { uint i; float f; } v; v.i = u << 16; return v.f; }
__device__ inline float bfhi(uint u) { union { uint i; float f; } v; v.i = u & 0xffff0000u; return v.f; }
__device__ inline ushort f2bf(float f) {
  union { float f; uint i; } v; v.f = f;
  uint i = v.i;
  return (ushort)((i + 0x7fffu + ((i >> 16) & 1u)) >> 16);  // RNE
}

#if __has_builtin(__builtin_amdgcn_cvt_pk_f32_fp8) && __has_builtin(__builtin_amdgcn_cvt_pk_fp8_f32)
#define HW_FP8 1
#endif

// decode 2 packed e4m3 (low 2 bytes of raw) -> 2 floats
__device__ inline f32x2v fp8x2_dec(uint raw) {
#ifdef HW_FP8
  return __builtin_amdgcn_cvt_pk_f32_fp8(raw, false);
#else
  f32x2v r;
#pragma unroll
  for (int i = 0; i < 2; ++i) {
    uint b = (raw >> (8 * i)) & 0xffu;
    uint em = b & 0x7fu;
    union { uint u; float f; } o;
    o.u = ((b & 0x80u) << 24) | (0x3C000000u + (em << 20));
    r[i] = (em >= 8u) ? o.f : 0.f;  // flush subnormals (encoder flushes too)
  }
  return r;
#endif
}

__device__ inline uint fp8enc1(float x) {
  union { float f; uint u; } v; v.f = x;
  uint s = (v.u >> 24) & 0x80u;
  uint a = v.u & 0x7fffffffu;
  if (a >= 0x43E00000u) return s | 0x7Eu;          // clamp to 448
  uint r = a + 0x7FFFFu + ((a >> 20) & 1u);        // RNE at bit 20
  if (r < 0x3D800000u) return s;                   // flush below min normal 2^-6
  return s | (((r - 0x3C000000u) >> 20) & 0x7fu);
}

// pack f0,f1 into low (HI=false) or high (HI=true) 2 bytes of old
template<bool HI>
__device__ inline uint fp8x2_enc(float f0, float f1, uint old) {
#ifdef HW_FP8
  return __builtin_amdgcn_cvt_pk_fp8_f32(f0, f1, old, HI);
#else
  uint p = fp8enc1(f0) | (fp8enc1(f1) << 8);
  return HI ? ((old & 0x0000ffffu) | (p << 16)) : ((old & 0xffff0000u) | p);
#endif
}

// ---------------- graph prep ----------------
__global__ void k_init(int* cnt, int n) {
  int i = blockIdx.x * BLK + threadIdx.x;
  if (i < n) cnt[i] = 0;
}

__global__ void k_count(const int* __restrict__ dst, int* cnt,
                        int* __restrict__ rank, int e) {
  int i = blockIdx.x * BLK + threadIdx.x;
  if (i < e) rank[i] = atomicAdd(&cnt[dst[i]], 1);
}

__global__ void k_scan1(const int* __restrict__ cnt, int* __restrict__ rowp,
                        int* __restrict__ bsum, int n) {
  __shared__ int s[BLK];
  int t = threadIdx.x;
  int i = blockIdx.x * BLK + t;
  int v = (i < n) ? cnt[i] : 0;
  s[t] = v; __syncthreads();
  for (int off = 1; off < BLK; off <<= 1) {
    int u = (t >= off) ? s[t - off] : 0;
    __syncthreads();
    s[t] += u;
    __syncthreads();
  }
  if (i < n) rowp[i] = s[t] - v;
  if (t == BLK - 1) bsum[blockIdx.x] = s[t];
}

__global__ void k_scan2(const int* __restrict__ bsum, int* __restrict__ boff, int nb) {
  __shared__ int s[BLK];
  int t = threadIdx.x;
  int v = (t < nb) ? bsum[t] : 0;
  s[t] = v; __syncthreads();
  for (int off = 1; off < BLK; off <<= 1) {
    int u = (t >= off) ? s[t - off] : 0;
    __syncthreads();
    s[t] += u;
    __syncthreads();
  }
  if (t < nb) boff[t] = s[t] - v;
}

__global__ void k_scan3(const int* __restrict__ boff, int* __restrict__ rowp,
                        const int* __restrict__ cnt, float* __restrict__ dinv,
                        int n, int e) {
  int i = blockIdx.x * BLK + threadIdx.x;
  if (i < n) {
    rowp[i] += boff[blockIdx.x];
    dinv[i] = rsqrtf((float)cnt[i] + 1.0f);
    if (i == 0) rowp[n] = e;
  }
}

__global__ void k_fill(const int* __restrict__ src, const int* __restrict__ dst,
                       const int* __restrict__ rowp, const int* __restrict__ rank,
                       int* __restrict__ csrc, int e) {
  int i = blockIdx.x * BLK + threadIdx.x;
  if (i < e) {
    int d = dst[i];
    csrc[rowp[d] + rank[i]] = src[i];
  }
}

// ---------------- weight packing (bf16 MFMA fragment order) ----------------
__global__ void k_pack(const float* __restrict__ W1, const float* __restrict__ T1,
                       const float* __restrict__ W2, const float* __restrict__ T2,
                       const float* __restrict__ lw1, const float* __restrict__ lw2,
                       ushort* __restrict__ Bpk1, ushort* __restrict__ Bpk2,
                       ushort* __restrict__ Bpkl, ushort* __restrict__ Bpk2l) {
  int idx = blockIdx.x * BLK + threadIdx.x;
  if (idx < 65536) {
    int which = idx >> 15;
    int e = idx & 32767;
    int k = e >> 8, c = e & 255;
    const float* W = which ? W2 : W1;
    const float* T = which ? T2 : T1;
    float v;
    if (c < 128) {
      v = T[k * 128 + c];
    } else {
      int cc = c - 128;  // (M^T)[k][cc] = W[cc][k] - W[k][cc] - g*delta
      v = W[cc * 128 + k] - W[k * 128 + cc] - ((cc == k) ? GAMMA_ : 0.f);
    }
    int kt = k >> 5, q = (k >> 3) & 3, j = k & 7;
    ushort* B = which ? Bpk2 : Bpk1;
    B[(((kt * 4 + q) * 256 + c) << 3) + j] = f2bf(v);
  } else if (idx < 81920) {
    int e = idx - 65536;
    int k = e >> 7, c = e & 127;
    float v = lw1[c * 128 + k];  // lw1^T[k][c]
    int kt = k >> 5, q = (k >> 3) & 3, j = k & 7;
    Bpkl[(((kt * 4 + q) * 128 + c) << 3) + j] = f2bf(v);
  } else {
    int e = idx - 81920;
    if (e < 6144) {
      int k = e / 48, c = e - k * 48;
      float v = (c < 40) ? lw2[c * 128 + k] : 0.f;  // lw2^T[k][c], zero-padded
      int kt = k >> 5, q = (k >> 3) & 3, j = k & 7;
      Bpk2l[(((kt * 4 + q) * 48 + c) << 3) + j] = f2bf(v);
    }
  }
}

// ---------------- MFMA bf16 GEMM, BM=32: C[nrows,NC] = A[nrows,128] @ B[128,NC] ----
// SPLIT: cols 0..127 -> Oq = fp8(v*dinv[row]); cols 128..255 -> O1 bf16 (xm).
// !SPLIT: O0 = bf16(relu(C+bias)).
template<int NC, bool SPLIT, bool FP32A>
__global__ __launch_bounds__(256) void k_mgemm(
    const void* __restrict__ Av, int nrows,
    const ushort* __restrict__ Bpk, const float* __restrict__ bias,
    const float* __restrict__ dinv,
    ushort* __restrict__ O0, ushort* __restrict__ O1, u8* __restrict__ Oq) {
  constexpr int NCW = NC / 4;   // cols per wave
  constexpr int NT = NCW / 16;  // 16x16 tiles per wave
  __shared__ ushort Cs[32 * NC];
  const int t = threadIdx.x;
  const int w = t >> 6, l = t & 63;
  const int lr = l & 15, lq = l >> 4;
  const int r0 = blockIdx.x * 32;
  const int ar0 = min(r0 + lr, nrows - 1);
  const int ar1 = min(r0 + 16 + lr, nrows - 1);
  f32x4 acc[2][NT];
#pragma unroll
  for (int rf = 0; rf < 2; ++rf)
#pragma unroll
    for (int n = 0; n < NT; ++n) acc[rf][n] = f32x4{0.f, 0.f, 0.f, 0.f};
#pragma unroll
  for (int kt = 0; kt < 4; ++kt) {
    short8 af0, af1;
    if (FP32A) {
      const float* Ap0 = (const float*)Av + (size_t)ar0 * 128 + lq * 8 + kt * 32;
      const float* Ap1 = (const float*)Av + (size_t)ar1 * 128 + lq * 8 + kt * 32;
      float4 a0 = *(const float4*)(Ap0), a0b = *(const float4*)(Ap0 + 4);
      float4 a1 = *(const float4*)(Ap1), a1b = *(const float4*)(Ap1 + 4);
      af0[0] = (short)f2bf(a0.x); af0[1] = (short)f2bf(a0.y);
      af0[2] = (short)f2bf(a0.z); af0[3] = (short)f2bf(a0.w);
      af0[4] = (short)f2bf(a0b.x); af0[5] = (short)f2bf(a0b.y);
      af0[6] = (short)f2bf(a0b.z); af0[7] = (short)f2bf(a0b.w);
      af1[0] = (short)f2bf(a1.x); af1[1] = (short)f2bf(a1.y);
      af1[2] = (short)f2bf(a1.z); af1[3] = (short)f2bf(a1.w);
      af1[4] = (short)f2bf(a1b.x); af1[5] = (short)f2bf(a1b.y);
      af1[6] = (short)f2bf(a1b.z); af1[7] = (short)f2bf(a1b.w);
    } else {
      af0 = *(const short8*)((const ushort*)Av + (size_t)ar0 * 128 + lq * 8 + kt * 32);
      af1 = *(const short8*)((const ushort*)Av + (size_t)ar1 * 128 + lq * 8 + kt * 32);
    }
    const ushort* bbase = Bpk + ((size_t)((kt * 4 + lq) * NC) + w * NCW + lr) * 8;
#pragma unroll
    for (int n = 0; n < NT; ++n) {
      short8 bf = *(const short8*)(bbase + n * 16 * 8);
      acc[0][n] = __builtin_amdgcn_mfma_f32_16x16x32_bf16(af0, bf, acc[0][n], 0, 0, 0);
      acc[1][n] = __builtin_amdgcn_mfma_f32_16x16x32_bf16(af1, bf, acc[1][n], 0, 0, 0);
    }
  }
  // stage to LDS with XOR bank-swizzle (spread lq across banks)
#pragma unroll
  for (int rf = 0; rf < 2; ++rf)
#pragma unroll
    for (int n = 0; n < NT; ++n)
#pragma unroll
      for (int r = 0; r < 4; ++r) {
        int row = rf * 16 + lq * 4 + r;
        int col = w * NCW + n * 16 + lr;
        float v = acc[rf][n][r];
        if (!SPLIT) v = fmaxf(v + bias[col], 0.f);
        int pcol = col ^ (((row >> 2) & 3) << 3);
        Cs[row * NC + pcol] = f2bf(v);
      }
  __syncthreads();
  if (SPLIT) {
    // xm half (cols 128..255) -> O1 bf16
#pragma unroll
    for (int it = 0; it < 2; ++it) {
      int idx = it * 256 + t;
      int row = idx >> 4, c8 = idx & 15;
      if (r0 + row < nrows) {
        int pc = (16 + (c8 ^ ((row >> 2) & 3))) * 8;
        uint4 v = *(const uint4*)(Cs + row * 256 + pc);
        *(uint4*)(O1 + (size_t)(r0 + row) * 128 + c8 * 8) = v;
      }
    }
    // xw half (cols 0..127): scale by dinv, encode fp8 -> Oq
#pragma unroll
    for (int it = 0; it < 2; ++it) {
      int idx = it * 256 + t;
      int row = idx >> 4, c8 = idx & 15;
      if (r0 + row < nrows) {
        float di = dinv[r0 + row];
        int pc = (c8 ^ ((row >> 2) & 3)) * 8;
        const uint* p = (const uint*)(Cs + row * 256 + pc);
        uint u0 = p[0], u1 = p[1], u2 = p[2], u3 = p[3];
        uint lo = fp8x2_enc<false>(bflo(u0) * di, bfhi(u0) * di, 0u);
        lo = fp8x2_enc<true>(bflo(u1) * di, bfhi(u1) * di, lo);
        uint hi = fp8x2_enc<false>(bflo(u2) * di, bfhi(u2) * di, 0u);
        hi = fp8x2_enc<true>(bflo(u3) * di, bfhi(u3) * di, hi);
        uint2 ov = { lo, hi };
        *(uint2*)(Oq + (size_t)(r0 + row) * 128 + c8 * 8) = ov;
      }
    }
  } else {
#pragma unroll
    for (int it = 0; it < 2; ++it) {
      int idx = it * 256 + t;
      int row = idx >> 4, c8 = idx & 15;
      if (r0 + row < nrows) {
        int pc = (c8 ^ ((row >> 2) & 3)) * 8;
        uint4 v = *(const uint4*)(Cs + row * 128 + pc);
        *(uint4*)(O0 + (size_t)(r0 + row) * 128 + c8 * 8) = v;
      }
    }
  }
}

// ---------------- fused aggregate + antisym combine (+relu) ----------------
// xq = fp8(xw*dinv) gather table [n,128] bytes.
// h = dinv[node]*(xq[node] + sum_e xq[src]) + xm[node] + bias
// out = relu( xin + 0.1*tanh(h) )
template<bool XIN_BF, bool OUT_BF>
__global__ __launch_bounds__(256) void k_aggc(
    const u8* __restrict__ xq, const ushort* __restrict__ xmb,
    const float* __restrict__ xinf, const ushort* __restrict__ xinb,
    const float* __restrict__ dinv,
    const int* __restrict__ rowp, const int* __restrict__ csrc,
    const float* __restrict__ bias,
    float* __restrict__ outf, ushort* __restrict__ outb, int n) {
  int node = blockIdx.x * 4 + (threadIdx.x >> 6);
  if (node >= n) return;
  int l = threadIdx.x & 63;  // features 2l, 2l+1
  uint su = *(const ushort*)(xq + (size_t)node * 128 + 2 * l);
  f32x2v sf = fp8x2_dec(su);
  float a0 = sf[0], a1 = sf[1];
  int e0 = rowp[node], e1 = rowp[node + 1];
  int e = e0;
  for (; e + 7 < e1; e += 8) {
    int s[8];
#pragma unroll
    for (int u = 0; u < 8; ++u) s[u] = csrc[e + u];
    uint g[8];
#pragma unroll
    for (int u = 0; u < 8; ++u)
      g[u] = *(const ushort*)(xq + (size_t)s[u] * 128 + 2 * l);
#pragma unroll
    for (int u = 0; u < 8; ++u) {
      f32x2v f = fp8x2_dec(g[u]);
      a0 += f[0]; a1 += f[1];
    }
  }
  if (e + 3 < e1) {
    int s[4];
#pragma unroll
    for (int u = 0; u < 4; ++u) s[u] = csrc[e + u];
    uint g[4];
#pragma unroll
    for (int u = 0; u < 4; ++u)
      g[u] = *(const ushort*)(xq + (size_t)s[u] * 128 + 2 * l);
#pragma unroll
    for (int u = 0; u < 4; ++u) {
      f32x2v f = fp8x2_dec(g[u]);
      a0 += f[0]; a1 += f[1];
    }
    e += 4;
  }
  for (; e < e1; ++e) {
    uint g0 = *(const ushort*)(xq + (size_t)csrc[e] * 128 + 2 * l);
    f32x2v f = fp8x2_dec(g0);
    a0 += f[0]; a1 += f[1];
  }
  float di = dinv[node];
  uint mu = *(const uint*)(xmb + (size_t)node * 128 + 2 * l);
  float h0 = a0 * di + bflo(mu) + bias[2 * l];
  float h1 = a1 * di + bfhi(mu) + bias[2 * l + 1];
  float x0, x1v;
  if (XIN_BF) {
    uint xu = *(const uint*)(xinb + (size_t)node * 128 + 2 * l);
    x0 = bflo(xu); x1v = bfhi(xu);
  } else {
    float2 xv = *(const float2*)(xinf + (size_t)node * 128 + 2 * l);
    x0 = xv.x; x1v = xv.y;
  }
  float o0 = fmaxf(x0 + EPS_ * tanhf(h0), 0.f);
  float o1 = fmaxf(x1v + EPS_ * tanhf(h1), 0.f);
  if (OUT_BF) {
    ushort2 o = { f2bf(o0), f2bf(o1) };
    *(ushort2*)(outb + (size_t)node * 128 + 2 * l) = o;
  } else {
    float2 o = { o0, o1 };
    *(float2*)(outf + (size_t)node * 128 + 2 * l) = o;
  }
}

// ---------------- fused final linear (MFMA) + log_softmax ----------------
__global__ __launch_bounds__(256) void k_logits2(
    const float* __restrict__ X, const ushort* __restrict__ Bpk,
    const float* __restrict__ lb2, float* __restrict__ out, int n) {
  __shared__ float Ls[64 * 49];
  __shared__ float bl[48];
  const int t = threadIdx.x;
  if (t < 48) bl[t] = (t < 40) ? lb2[t] : 0.f;
  const int w = t >> 6, l = t & 63;
  const int lr = l & 15, lq = l >> 4;
  const int r0 = blockIdx.x * 64;
  const int ar = min(r0 + w * 16 + lr, n - 1);
  const float* Ap = X + (size_t)ar * 128 + lq * 8;
  f32x4 acc[3];
#pragma unroll
  for (int nn = 0; nn < 3; ++nn) acc[nn] = f32x4{0.f, 0.f, 0.f, 0.f};
#pragma unroll
  for (int kt = 0; kt < 4; ++kt) {
    float4 xa = *(const float4*)(Ap + kt * 32);
    float4 xc = *(const float4*)(Ap + kt * 32 + 4);
    short8 af;
    af[0] = (short)f2bf(xa.x); af[1] = (short)f2bf(xa.y);
    af[2] = (short)f2bf(xa.z); af[3] = (short)f2bf(xa.w);
    af[4] = (short)f2bf(xc.x); af[5] = (short)f2bf(xc.y);
    af[6] = (short)f2bf(xc.z); af[7] = (short)f2bf(xc.w);
    const ushort* bbase = Bpk + ((size_t)((kt * 4 + lq) * 48) + lr) * 8;
#pragma unroll
    for (int nn = 0; nn < 3; ++nn) {
      short8 bf = *(const short8*)(bbase + nn * 16 * 8);
      acc[nn] = __builtin_amdgcn_mfma_f32_16x16x32_bf16(af, bf, acc[nn], 0, 0, 0);
    }
  }
  __syncthreads();  // bl ready
#pragma unroll
  for (int nn = 0; nn < 3; ++nn)
#pragma unroll
    for (int r = 0; r < 4; ++r) {
      int row = w * 16 + lq * 4 + r;
      int col = nn * 16 + lr;
      Ls[row * 49 + col] = acc[nn][r] + bl[col];
    }
  __syncthreads();
  int row = t >> 2, q = t & 3;
  if (r0 + row >= n) return;
  const float* Lr = Ls + row * 49 + q * 10;
  float m = -1e30f;
#pragma unroll
  for (int c = 0; c < 10; ++c) m = fmaxf(m, Lr[c]);
  m = fmaxf(m, __shfl_xor(m, 1));
  m = fmaxf(m, __shfl_xor(m, 2));
  float s = 0.f;
#pragma unroll
  for (int c = 0; c < 10; ++c) s += expf(Lr[c] - m);
  s += __shfl_xor(s, 1);
  s += __shfl_xor(s, 2);
  float lse = m + logf(s);
  float* Or = out + (size_t)(r0 + row) * 40 + q * 10;
#pragma unroll
  for (int c = 0; c < 10; ++c) Or[c] = Lr[c] - lse;
}

// ---------------- launch ----------------
extern "C" void kernel_launch(void* const* d_in, const int* in_sizes, int n_in,
                              void* d_out, int out_size, void* d_ws, size_t ws_size,
                              hipStream_t stream) {
  const float* x   = (const float*)d_in[0];
  const int*   ei  = (const int*)d_in[1];
  const float* W1  = (const float*)d_in[2];
  const float* b1  = (const float*)d_in[3];
  const float* T1  = (const float*)d_in[4];
  const float* W2  = (const float*)d_in[5];
  const float* b2  = (const float*)d_in[6];
  const float* T2  = (const float*)d_in[7];
  const float* lw1 = (const float*)d_in[8];
  const float* lb1 = (const float*)d_in[9];
  const float* lw2 = (const float*)d_in[10];
  const float* lb2 = (const float*)d_in[11];
  const int N = in_sizes[0] / 128;
  const int E = in_sizes[1] / 2;
  const int* src = ei;
  const int* dst = ei + E;

  float* ws = (float*)d_ws;
  size_t o = 0;
  float* dinv = ws;             o += N;
  int* cnt = (int*)(ws + o);    o += N;
  int* rowp = (int*)(ws + o);   o += (size_t)(N + 4);
  int* csrc = (int*)(ws + o);   o += E;
  int* rank = (int*)(ws + o);   o += E;
  int* bsum = (int*)(ws + o);   o += 256;
  int* boff = (int*)(ws + o);   o += 256;
  o = (o + 3) & ~(size_t)3;     // 16B align
  ushort* us = (ushort*)(ws + o);
  size_t uo = 0;
  ushort* Bpk1 = us + uo;       uo += 32768;
  ushort* Bpk2 = us + uo;       uo += 32768;
  ushort* Bpkl = us + uo;       uo += 16384;
  ushort* Bpk2l = us + uo;      uo += 6144;
  ushort* xmb  = us + uo;       uo += (size_t)N * 128;
  ushort* h1b  = us + uo;       uo += (size_t)N * 128;
  ushort* h2b  = us + uo;       uo += (size_t)N * 128;
  u8* xq = (u8*)(us + uo);      // N*128 bytes

  float* outp = (float*)d_out;
  float* x1 = outp + (size_t)N * 40;

  int nb_n = (N + BLK - 1) / BLK;
  int nb_e = (E + BLK - 1) / BLK;
  int nb_r = (N + 31) / 32;

  k_init<<<nb_n, BLK, 0, stream>>>(cnt, N);
  k_count<<<nb_e, BLK, 0, stream>>>(dst, cnt, rank, E);
  k_scan1<<<nb_n, BLK, 0, stream>>>(cnt, rowp, bsum, N);
  k_scan2<<<1, BLK, 0, stream>>>(bsum, boff, nb_n);
  k_scan3<<<nb_n, BLK, 0, stream>>>(boff, rowp, cnt, dinv, N, E);
  k_fill<<<nb_e, BLK, 0, stream>>>(src, dst, rowp, rank, csrc, E);
  k_pack<<<344, BLK, 0, stream>>>(W1, T1, W2, T2, lw1, lw2, Bpk1, Bpk2, Bpkl, Bpk2l);

  // layer 1: [xq | xm] = x @ [T1 | M1^T]  (fp32 A; xw scaled by dinv, fp8-encoded)
  k_mgemm<256, true, true><<<nb_r, 256, 0, stream>>>(
      x, N, Bpk1, nullptr, dinv, nullptr, xmb, xq);
  k_aggc<false, true><<<(N + 3) / 4, 256, 0, stream>>>(
      xq, xmb, x, nullptr, dinv, rowp, csrc, b1, nullptr, h1b, N);
  // linear 1 + relu
  k_mgemm<128, false, false><<<nb_r, 256, 0, stream>>>(
      h1b, N, Bpkl, lb1, nullptr, h2b, nullptr, nullptr);
  // layer 2
  k_mgemm<256, true, false><<<nb_r, 256, 0, stream>>>(
      h2b, N, Bpk2, nullptr, dinv, nullptr, xmb, xq);
  k_aggc<true, false><<<(N + 3) / 4, 256, 0, stream>>>(
      xq, xmb, nullptr, h2b, dinv, rowp, csrc, b2, x1, nullptr, N);
  // linear 2 + log_softmax (MFMA)
  k_logits2<<<(N + 63) / 64, 256, 0, stream>>>(x1, Bpk2l, lb2, outp, N);
}

// Round 7
// 185.603 us; speedup vs baseline: 3.3135x; 1.0386x over previous
//
#include <hip/hip_runtime.h>
#include <hip/hip_bf16.h>
#include <math.h>

#define GAMMA_ 0.1f
#define EPS_ 0.1f
constexpr int BLK = 256;

typedef __attribute__((ext_vector_type(8))) short short8;
typedef __attribute__((ext_vector_type(4))) float f32x4;
typedef __attribute__((ext_vector_type(2))) float f32x2v;
typedef unsigned char u8;

__device__ inline float bflo(uint u) { union { uint i; float f; } v; v.i = u << 16; return v.f; }
__device__ inline float bfhi(uint u) { union { uint i; float f; } v; v.i = u & 0xffff0000u; return v.f; }
__device__ inline ushort f2bf(float f) {
  union { float f; uint i; } v; v.f = f;
  uint i = v.i;
  return (ushort)((i + 0x7fffu + ((i >> 16) & 1u)) >> 16);  // RNE
}

#if __has_builtin(__builtin_amdgcn_cvt_pk_f32_fp8) && __has_builtin(__builtin_amdgcn_cvt_pk_fp8_f32)
#define HW_FP8 1
#endif

__device__ inline f32x2v fp8x2_dec(uint raw) {
#ifdef HW_FP8
  return __builtin_amdgcn_cvt_pk_f32_fp8(raw, false);
#else
  f32x2v r;
#pragma unroll
  for (int i = 0; i < 2; ++i) {
    uint b = (raw >> (8 * i)) & 0xffu;
    uint em = b & 0x7fu;
    union { uint u; float f; } o;
    o.u = ((b & 0x80u) << 24) | (0x3C000000u + (em << 20));
    r[i] = (em >= 8u) ? o.f : 0.f;
  }
  return r;
#endif
}

__device__ inline uint fp8enc1(float x) {
  union { float f; uint u; } v; v.f = x;
  uint s = (v.u >> 24) & 0x80u;
  uint a = v.u & 0x7fffffffu;
  if (a >= 0x43E00000u) return s | 0x7Eu;
  uint r = a + 0x7FFFFu + ((a >> 20) & 1u);
  if (r < 0x3D800000u) return s;
  return s | (((r - 0x3C000000u) >> 20) & 0x7fu);
}

template<bool HI>
__device__ inline uint fp8x2_enc(float f0, float f1, uint old) {
#ifdef HW_FP8
  return __builtin_amdgcn_cvt_pk_fp8_f32(f0, f1, old, HI);
#else
  uint p = fp8enc1(f0) | (fp8enc1(f1) << 8);
  return HI ? ((old & 0x0000ffffu) | (p << 16)) : ((old & 0xffff0000u) | p);
#endif
}

// ---------------- graph prep ----------------
__global__ void k_count(const int* __restrict__ dst, int* cnt,
                        int* __restrict__ rank, int e) {
  int i = blockIdx.x * BLK + threadIdx.x;
  if (i < e) rank[i] = atomicAdd(&cnt[dst[i]], 1);
}

__global__ void k_scan1(const int* __restrict__ cnt, int* __restrict__ rowp,
                        int* __restrict__ bsum, int n) {
  __shared__ int s[BLK];
  int t = threadIdx.x;
  int i = blockIdx.x * BLK + t;
  int v = (i < n) ? cnt[i] : 0;
  s[t] = v; __syncthreads();
  for (int off = 1; off < BLK; off <<= 1) {
    int u = (t >= off) ? s[t - off] : 0;
    __syncthreads();
    s[t] += u;
    __syncthreads();
  }
  if (i < n) rowp[i] = s[t] - v;
  if (t == BLK - 1) bsum[blockIdx.x] = s[t];
}

__global__ void k_scan2(const int* __restrict__ bsum, int* __restrict__ boff, int nb) {
  __shared__ int s[BLK];
  int t = threadIdx.x;
  int v = (t < nb) ? bsum[t] : 0;
  s[t] = v; __syncthreads();
  for (int off = 1; off < BLK; off <<= 1) {
    int u = (t >= off) ? s[t - off] : 0;
    __syncthreads();
    s[t] += u;
    __syncthreads();
  }
  if (t < nb) boff[t] = s[t] - v;
}

__global__ void k_scan3(const int* __restrict__ boff, int* __restrict__ rowp,
                        const int* __restrict__ cnt, float* __restrict__ dinv,
                        int n, int e) {
  int i = blockIdx.x * BLK + threadIdx.x;
  if (i < n) {
    rowp[i] += boff[blockIdx.x];
    dinv[i] = rsqrtf((float)cnt[i] + 1.0f);
    if (i == 0) rowp[n] = e;
  }
}

__global__ void k_fill(const int* __restrict__ src, const int* __restrict__ dst,
                       const int* __restrict__ rowp, const int* __restrict__ rank,
                       int* __restrict__ csrc, int e) {
  int i = blockIdx.x * BLK + threadIdx.x;
  if (i < e) {
    int d = dst[i];
    csrc[rowp[d] + rank[i]] = src[i];
  }
}

// ---------------- weight packing (bf16 MFMA fragment order) ----------------
__global__ void k_pack(const float* __restrict__ W1, const float* __restrict__ T1,
                       const float* __restrict__ W2, const float* __restrict__ T2,
                       const float* __restrict__ lw1, const float* __restrict__ lw2,
                       ushort* __restrict__ Bpk1, ushort* __restrict__ Bpk2,
                       ushort* __restrict__ Bpkl, ushort* __restrict__ Bpk2l) {
  int idx = blockIdx.x * BLK + threadIdx.x;
  if (idx < 65536) {
    int which = idx >> 15;
    int e = idx & 32767;
    int k = e >> 8, c = e & 255;
    const float* W = which ? W2 : W1;
    const float* T = which ? T2 : T1;
    float v;
    if (c < 128) {
      v = T[k * 128 + c];
    } else {
      int cc = c - 128;  // (M^T)[k][cc] = W[cc][k] - W[k][cc] - g*delta
      v = W[cc * 128 + k] - W[k * 128 + cc] - ((cc == k) ? GAMMA_ : 0.f);
    }
    int kt = k >> 5, q = (k >> 3) & 3, j = k & 7;
    ushort* B = which ? Bpk2 : Bpk1;
    B[(((kt * 4 + q) * 256 + c) << 3) + j] = f2bf(v);
  } else if (idx < 81920) {
    int e = idx - 65536;
    int k = e >> 7, c = e & 127;
    float v = lw1[c * 128 + k];  // lw1^T[k][c]
    int kt = k >> 5, q = (k >> 3) & 3, j = k & 7;
    Bpkl[(((kt * 4 + q) * 128 + c) << 3) + j] = f2bf(v);
  } else {
    int e = idx - 81920;
    if (e < 6144) {
      int k = e / 48, c = e - k * 48;
      float v = (c < 40) ? lw2[c * 128 + k] : 0.f;  // lw2^T[k][c], zero-padded
      int kt = k >> 5, q = (k >> 3) & 3, j = k & 7;
      Bpk2l[(((kt * 4 + q) * 48 + c) << 3) + j] = f2bf(v);
    }
  }
}

// ---------------- MFMA bf16 GEMM, BM=64, NC=256, LDS-staged A ----------------
// C[nrows,256] = A[nrows,128] @ B[128,256]
// cols 0..127 -> Oq = fp8(v*dinv[row]); cols 128..255 -> O1 bf16 (xm).
template<bool FP32A>
__global__ __launch_bounds__(256) void k_mgemm(
    const void* __restrict__ Av, int nrows,
    const ushort* __restrict__ Bpk, const float* __restrict__ dinv,
    ushort* __restrict__ O1, u8* __restrict__ Oq) {
  __shared__ ushort S[64 * 256];       // 32KB; first 16KB = A-stage, then reused as C-stage
  const int t = threadIdx.x;
  const int w = t >> 6, l = t & 63;
  const int lr = l & 15, lq = l >> 4;
  const int r0 = blockIdx.x * 64;
  // ---- stage A (64 rows x 128, bf16, XOR-swizzled 16B chunks) ----
#pragma unroll
  for (int it = 0; it < 4; ++it) {
    int chunk = it * 256 + t;          // 1024 chunks of 8 elems
    int row = chunk >> 4, c16 = chunk & 15;
    int gr = min(r0 + row, nrows - 1);
    ushort* p = S + row * 128 + (c16 ^ (row & 7)) * 8;
    if (FP32A) {
      const float* A = (const float*)Av + (size_t)gr * 128 + c16 * 8;
      float4 v0 = *(const float4*)(A);
      float4 v1 = *(const float4*)(A + 4);
      ushort4 o0 = {f2bf(v0.x), f2bf(v0.y), f2bf(v0.z), f2bf(v0.w)};
      ushort4 o1 = {f2bf(v1.x), f2bf(v1.y), f2bf(v1.z), f2bf(v1.w)};
      *(ushort4*)(p) = o0;
      *(ushort4*)(p + 4) = o1;
    } else {
      const ushort* A = (const ushort*)Av + (size_t)gr * 128 + c16 * 8;
      *(uint4*)p = *(const uint4*)A;
    }
  }
  __syncthreads();
  // ---- MFMA: wave w owns cols [w*64, w*64+64) ----
  f32x4 acc[4][4];
#pragma unroll
  for (int rt = 0; rt < 4; ++rt)
#pragma unroll
    for (int n = 0; n < 4; ++n) acc[rt][n] = f32x4{0.f, 0.f, 0.f, 0.f};
#pragma unroll
  for (int kt = 0; kt < 4; ++kt) {
    short8 af[4];
#pragma unroll
    for (int rt = 0; rt < 4; ++rt) {
      int row = rt * 16 + lr;
      af[rt] = *(const short8*)(S + row * 128 + ((kt * 4 + lq) ^ (row & 7)) * 8);
    }
    const ushort* bbase = Bpk + ((size_t)((kt * 4 + lq) * 256) + w * 64 + lr) * 8;
#pragma unroll
    for (int n = 0; n < 4; ++n) {
      short8 bf = *(const short8*)(bbase + n * 16 * 8);
#pragma unroll
      for (int rt = 0; rt < 4; ++rt)
        acc[rt][n] = __builtin_amdgcn_mfma_f32_16x16x32_bf16(af[rt], bf, acc[rt][n], 0, 0, 0);
    }
  }
  __syncthreads();  // done reading A-stage
  // ---- stage C (bf16, col-swizzled) ----
#pragma unroll
  for (int rt = 0; rt < 4; ++rt)
#pragma unroll
    for (int n = 0; n < 4; ++n)
#pragma unroll
      for (int r = 0; r < 4; ++r) {
        int row = rt * 16 + lq * 4 + r;
        int col = w * 64 + n * 16 + lr;
        int pcol = col ^ (((row >> 2) & 3) << 3);
        S[row * 256 + pcol] = f2bf(acc[rt][n][r]);
      }
  __syncthreads();
  // xm half (cols 128..255) -> O1 bf16
#pragma unroll
  for (int it = 0; it < 4; ++it) {
    int idx = it * 256 + t;
    int row = idx >> 4, c8 = idx & 15;
    if (r0 + row < nrows) {
      int pc = (16 + (c8 ^ ((row >> 2) & 3))) * 8;
      uint4 v = *(const uint4*)(S + row * 256 + pc);
      *(uint4*)(O1 + (size_t)(r0 + row) * 128 + c8 * 8) = v;
    }
  }
  // xw half (cols 0..127): scale by dinv, fp8 -> Oq
#pragma unroll
  for (int it = 0; it < 4; ++it) {
    int idx = it * 256 + t;
    int row = idx >> 4, c8 = idx & 15;
    if (r0 + row < nrows) {
      float di = dinv[r0 + row];
      int pc = (c8 ^ ((row >> 2) & 3)) * 8;
      const uint* p = (const uint*)(S + row * 256 + pc);
      uint u0 = p[0], u1 = p[1], u2 = p[2], u3 = p[3];
      uint lo = fp8x2_enc<false>(bflo(u0) * di, bfhi(u0) * di, 0u);
      lo = fp8x2_enc<true>(bflo(u1) * di, bfhi(u1) * di, lo);
      uint hi = fp8x2_enc<false>(bflo(u2) * di, bfhi(u2) * di, 0u);
      hi = fp8x2_enc<true>(bflo(u3) * di, bfhi(u3) * di, hi);
      uint2 ov = { lo, hi };
      *(uint2*)(Oq + (size_t)(r0 + row) * 128 + c8 * 8) = ov;
    }
  }
}

// ---------------- fused aggc(layer1) + linear1(+bias,relu) ----------------
// Phase 1: per 32-node block (8 waves, 4 nodes/wave):
//   h1 = relu( x + 0.1*tanh( dinv*(xq[node]+sum xq[src]) + xm + b1 ) ) -> LDS (bf16, swizzled)
// Phase 2: h2 = relu(h1 @ lw1^T + lb1) -> h2b (bf16)
__global__ __launch_bounds__(512) void k_aggl(
    const u8* __restrict__ xq, const ushort* __restrict__ xmb,
    const float* __restrict__ xinf, const float* __restrict__ dinv,
    const int* __restrict__ rowp, const int* __restrict__ csrc,
    const float* __restrict__ bias, const ushort* __restrict__ Bpkl,
    const float* __restrict__ lb1, ushort* __restrict__ h2b, int n) {
  __shared__ ushort Hs[32 * 128];      // 8KB
  const int t = threadIdx.x;
  const int w = t >> 6, l = t & 63;
  const int lr = l & 15, lq = l >> 4;
  const int r0 = blockIdx.x * 32;
#pragma unroll
  for (int i = 0; i < 4; ++i) {
    int lrow = w * 4 + i;
    int node = r0 + lrow;
    float o0 = 0.f, o1 = 0.f;
    if (node < n) {
      uint su = *(const ushort*)(xq + (size_t)node * 128 + 2 * l);
      f32x2v sf = fp8x2_dec(su);
      float a0 = sf[0], a1 = sf[1];
      int e0 = rowp[node], e1 = rowp[node + 1];
      int e = e0;
      for (; e + 7 < e1; e += 8) {
        int s[8];
#pragma unroll
        for (int u = 0; u < 8; ++u) s[u] = csrc[e + u];
        uint g[8];
#pragma unroll
        for (int u = 0; u < 8; ++u)
          g[u] = *(const ushort*)(xq + (size_t)s[u] * 128 + 2 * l);
#pragma unroll
        for (int u = 0; u < 8; ++u) {
          f32x2v f = fp8x2_dec(g[u]);
          a0 += f[0]; a1 += f[1];
        }
      }
      if (e + 3 < e1) {
        int s[4];
#pragma unroll
        for (int u = 0; u < 4; ++u) s[u] = csrc[e + u];
        uint g[4];
#pragma unroll
        for (int u = 0; u < 4; ++u)
          g[u] = *(const ushort*)(xq + (size_t)s[u] * 128 + 2 * l);
#pragma unroll
        for (int u = 0; u < 4; ++u) {
          f32x2v f = fp8x2_dec(g[u]);
          a0 += f[0]; a1 += f[1];
        }
        e += 4;
      }
      for (; e < e1; ++e) {
        uint g0 = *(const ushort*)(xq + (size_t)csrc[e] * 128 + 2 * l);
        f32x2v f = fp8x2_dec(g0);
        a0 += f[0]; a1 += f[1];
      }
      float di = dinv[node];
      uint mu = *(const uint*)(xmb + (size_t)node * 128 + 2 * l);
      float h0 = a0 * di + bflo(mu) + bias[2 * l];
      float h1 = a1 * di + bfhi(mu) + bias[2 * l + 1];
      float2 xv = *(const float2*)(xinf + (size_t)node * 128 + 2 * l);
      o0 = fmaxf(xv.x + EPS_ * tanhf(h0), 0.f);
      o1 = fmaxf(xv.y + EPS_ * tanhf(h1), 0.f);
    }
    // LDS store (cols 2l, 2l+1), 16B-chunk XOR swizzle
    ushort2 o = { f2bf(o0), f2bf(o1) };
    *(ushort2*)(Hs + lrow * 128 + ((l >> 2) ^ (lrow & 7)) * 8 + (l & 3) * 2) = o;
  }
  __syncthreads();
  // Phase 2: wave w -> col tile [w*16, w*16+16), row tiles 0..1
  f32x4 acc[2];
  acc[0] = f32x4{0.f, 0.f, 0.f, 0.f};
  acc[1] = f32x4{0.f, 0.f, 0.f, 0.f};
#pragma unroll
  for (int kt = 0; kt < 4; ++kt) {
    short8 bf = *(const short8*)(Bpkl + ((size_t)((kt * 4 + lq) * 128) + w * 16 + lr) * 8);
#pragma unroll
    for (int rt = 0; rt < 2; ++rt) {
      int row = rt * 16 + lr;
      short8 af = *(const short8*)(Hs + row * 128 + ((kt * 4 + lq) ^ (row & 7)) * 8);
      acc[rt] = __builtin_amdgcn_mfma_f32_16x16x32_bf16(af, bf, acc[rt], 0, 0, 0);
    }
  }
  int col = w * 16 + lr;
  float bv = lb1[col];
#pragma unroll
  for (int rt = 0; rt < 2; ++rt)
#pragma unroll
    for (int r = 0; r < 4; ++r) {
      int row = rt * 16 + lq * 4 + r;
      if (r0 + row < n)
        h2b[(size_t)(r0 + row) * 128 + col] = f2bf(fmaxf(acc[rt][r] + bv, 0.f));
    }
}

// ---------------- fused aggregate + antisym combine (+relu), layer 2 ----------------
__global__ __launch_bounds__(256) void k_aggc(
    const u8* __restrict__ xq, const ushort* __restrict__ xmb,
    const ushort* __restrict__ xinb, const float* __restrict__ dinv,
    const int* __restrict__ rowp, const int* __restrict__ csrc,
    const float* __restrict__ bias, float* __restrict__ outf, int n) {
  int node = blockIdx.x * 4 + (threadIdx.x >> 6);
  if (node >= n) return;
  int l = threadIdx.x & 63;
  uint su = *(const ushort*)(xq + (size_t)node * 128 + 2 * l);
  f32x2v sf = fp8x2_dec(su);
  float a0 = sf[0], a1 = sf[1];
  int e0 = rowp[node], e1 = rowp[node + 1];
  int e = e0;
  for (; e + 7 < e1; e += 8) {
    int s[8];
#pragma unroll
    for (int u = 0; u < 8; ++u) s[u] = csrc[e + u];
    uint g[8];
#pragma unroll
    for (int u = 0; u < 8; ++u)
      g[u] = *(const ushort*)(xq + (size_t)s[u] * 128 + 2 * l);
#pragma unroll
    for (int u = 0; u < 8; ++u) {
      f32x2v f = fp8x2_dec(g[u]);
      a0 += f[0]; a1 += f[1];
    }
  }
  if (e + 3 < e1) {
    int s[4];
#pragma unroll
    for (int u = 0; u < 4; ++u) s[u] = csrc[e + u];
    uint g[4];
#pragma unroll
    for (int u = 0; u < 4; ++u)
      g[u] = *(const ushort*)(xq + (size_t)s[u] * 128 + 2 * l);
#pragma unroll
    for (int u = 0; u < 4; ++u) {
      f32x2v f = fp8x2_dec(g[u]);
      a0 += f[0]; a1 += f[1];
    }
    e += 4;
  }
  for (; e < e1; ++e) {
    uint g0 = *(const ushort*)(xq + (size_t)csrc[e] * 128 + 2 * l);
    f32x2v f = fp8x2_dec(g0);
    a0 += f[0]; a1 += f[1];
  }
  float di = dinv[node];
  uint mu = *(const uint*)(xmb + (size_t)node * 128 + 2 * l);
  float h0 = a0 * di + bflo(mu) + bias[2 * l];
  float h1 = a1 * di + bfhi(mu) + bias[2 * l + 1];
  uint xu = *(const uint*)(xinb + (size_t)node * 128 + 2 * l);
  float o0 = fmaxf(bflo(xu) + EPS_ * tanhf(h0), 0.f);
  float o1 = fmaxf(bfhi(xu) + EPS_ * tanhf(h1), 0.f);
  float2 o = { o0, o1 };
  *(float2*)(outf + (size_t)node * 128 + 2 * l) = o;
}

// ---------------- fused final linear (MFMA) + log_softmax ----------------
__global__ __launch_bounds__(256) void k_logits2(
    const float* __restrict__ X, const ushort* __restrict__ Bpk,
    const float* __restrict__ lb2, float* __restrict__ out, int n) {
  __shared__ float Ls[64 * 49];
  __shared__ float bl[48];
  const int t = threadIdx.x;
  if (t < 48) bl[t] = (t < 40) ? lb2[t] : 0.f;
  const int w = t >> 6, l = t & 63;
  const int lr = l & 15, lq = l >> 4;
  const int r0 = blockIdx.x * 64;
  const int ar = min(r0 + w * 16 + lr, n - 1);
  const float* Ap = X + (size_t)ar * 128 + lq * 8;
  f32x4 acc[3];
#pragma unroll
  for (int nn = 0; nn < 3; ++nn) acc[nn] = f32x4{0.f, 0.f, 0.f, 0.f};
#pragma unroll
  for (int kt = 0; kt < 4; ++kt) {
    float4 xa = *(const float4*)(Ap + kt * 32);
    float4 xc = *(const float4*)(Ap + kt * 32 + 4);
    short8 af;
    af[0] = (short)f2bf(xa.x); af[1] = (short)f2bf(xa.y);
    af[2] = (short)f2bf(xa.z); af[3] = (short)f2bf(xa.w);
    af[4] = (short)f2bf(xc.x); af[5] = (short)f2bf(xc.y);
    af[6] = (short)f2bf(xc.z); af[7] = (short)f2bf(xc.w);
    const ushort* bbase = Bpk + ((size_t)((kt * 4 + lq) * 48) + lr) * 8;
#pragma unroll
    for (int nn = 0; nn < 3; ++nn) {
      short8 bf = *(const short8*)(bbase + nn * 16 * 8);
      acc[nn] = __builtin_amdgcn_mfma_f32_16x16x32_bf16(af, bf, acc[nn], 0, 0, 0);
    }
  }
  __syncthreads();
#pragma unroll
  for (int nn = 0; nn < 3; ++nn)
#pragma unroll
    for (int r = 0; r < 4; ++r) {
      int row = w * 16 + lq * 4 + r;
      int col = nn * 16 + lr;
      Ls[row * 49 + col] = acc[nn][r] + bl[col];
    }
  __syncthreads();
  int row = t >> 2, q = t & 3;
  if (r0 + row >= n) return;
  const float* Lr = Ls + row * 49 + q * 10;
  float m = -1e30f;
#pragma unroll
  for (int c = 0; c < 10; ++c) m = fmaxf(m, Lr[c]);
  m = fmaxf(m, __shfl_xor(m, 1));
  m = fmaxf(m, __shfl_xor(m, 2));
  float s = 0.f;
#pragma unroll
  for (int c = 0; c < 10; ++c) s += expf(Lr[c] - m);
  s += __shfl_xor(s, 1);
  s += __shfl_xor(s, 2);
  float lse = m + logf(s);
  float* Or = out + (size_t)(r0 + row) * 40 + q * 10;
#pragma unroll
  for (int c = 0; c < 10; ++c) Or[c] = Lr[c] - lse;
}

// ---------------- launch ----------------
extern "C" void kernel_launch(void* const* d_in, const int* in_sizes, int n_in,
                              void* d_out, int out_size, void* d_ws, size_t ws_size,
                              hipStream_t stream) {
  const float* x   = (const float*)d_in[0];
  const int*   ei  = (const int*)d_in[1];
  const float* W1  = (const float*)d_in[2];
  const float* b1  = (const float*)d_in[3];
  const float* T1  = (const float*)d_in[4];
  const float* W2  = (const float*)d_in[5];
  const float* b2  = (const float*)d_in[6];
  const float* T2  = (const float*)d_in[7];
  const float* lw1 = (const float*)d_in[8];
  const float* lb1 = (const float*)d_in[9];
  const float* lw2 = (const float*)d_in[10];
  const float* lb2 = (const float*)d_in[11];
  const int N = in_sizes[0] / 128;
  const int E = in_sizes[1] / 2;
  const int* src = ei;
  const int* dst = ei + E;

  float* ws = (float*)d_ws;
  size_t o = 0;
  float* dinv = ws;             o += N;
  int* cnt = (int*)(ws + o);    o += N;
  int* rowp = (int*)(ws + o);   o += (size_t)(N + 4);
  int* csrc = (int*)(ws + o);   o += E;
  int* rank = (int*)(ws + o);   o += E;
  int* bsum = (int*)(ws + o);   o += 256;
  int* boff = (int*)(ws + o);   o += 256;
  o = (o + 3) & ~(size_t)3;
  ushort* us = (ushort*)(ws + o);
  size_t uo = 0;
  ushort* Bpk1 = us + uo;       uo += 32768;
  ushort* Bpk2 = us + uo;       uo += 32768;
  ushort* Bpkl = us + uo;       uo += 16384;
  ushort* Bpk2l = us + uo;      uo += 6144;
  ushort* xmb  = us + uo;       uo += (size_t)N * 128;
  ushort* h2b  = us + uo;       uo += (size_t)N * 128;
  u8* xq = (u8*)(us + uo);      // N*128 bytes

  float* outp = (float*)d_out;
  float* x1 = outp + (size_t)N * 40;

  int nb_n = (N + BLK - 1) / BLK;
  int nb_e = (E + BLK - 1) / BLK;
  int nb_r = (N + 63) / 64;

  hipMemsetAsync(cnt, 0, (size_t)N * sizeof(int), stream);
  k_count<<<nb_e, BLK, 0, stream>>>(dst, cnt, rank, E);
  k_scan1<<<nb_n, BLK, 0, stream>>>(cnt, rowp, bsum, N);
  k_scan2<<<1, BLK, 0, stream>>>(bsum, boff, nb_n);
  k_scan3<<<nb_n, BLK, 0, stream>>>(boff, rowp, cnt, dinv, N, E);
  k_fill<<<nb_e, BLK, 0, stream>>>(src, dst, rowp, rank, csrc, E);
  k_pack<<<344, BLK, 0, stream>>>(W1, T1, W2, T2, lw1, lw2, Bpk1, Bpk2, Bpkl, Bpk2l);

  // layer 1 entry GEMM: [xq | xm] = x @ [T1 | M1^T]
  k_mgemm<true><<<nb_r, 256, 0, stream>>>(x, N, Bpk1, dinv, xmb, xq);
  // aggc layer1 + linear1 fused -> h2b
  k_aggl<<<(N + 31) / 32, 512, 0, stream>>>(
      xq, xmb, x, dinv, rowp, csrc, b1, Bpkl, lb1, h2b, N);
  // layer 2 entry GEMM
  k_mgemm<false><<<nb_r, 256, 0, stream>>>(h2b, N, Bpk2, dinv, xmb, xq);
  // aggc layer2 -> x1 (fp32, to d_out)
  k_aggc<<<(N + 3) / 4, 256, 0, stream>>>(
      xq, xmb, h2b, dinv, rowp, csrc, b2, x1, N);
  // final linear + log_softmax
  k_logits2<<<(N + 63) / 64, 256, 0, stream>>>(x1, Bpk2l, lb2, outp, N);
}